// Round 2
// 766.305 us; speedup vs baseline: 1.0145x; 1.0145x over previous
//
#include <hip/hip_runtime.h>

// ---------------------------------------------------------------------------
// SAGE_Re GNN forward, R7b (identical to R7; R7 bench was an infra failure).
// - GEMM: 3-stage LDS pipeline with COUNTED vmcnt (never drain to 0 in
//   steady state): raw s_barrier + s_waitcnt vmcnt(8/4/0); prefetch distance
//   2 chunks. Source-swizzled staging kills the 4-way ds_read_b128 phase
//   conflict. setprio(1) around the MFMA cluster.
// - agg: 4 gathers in flight for both C=128 and C=256.
// - CSR: 3-phase multi-block scan (R5).
// ---------------------------------------------------------------------------

typedef __attribute__((ext_vector_type(8))) short bf16x8;
typedef __attribute__((ext_vector_type(4))) float f32x4;

__device__ __forceinline__ float bf2f(unsigned short u) {
    union { unsigned int i; float f; } v; v.i = ((unsigned int)u) << 16; return v.f;
}
__device__ __forceinline__ unsigned short f2bf(float f) {
    union { float f; unsigned int i; } v; v.f = f;
    unsigned int r = (v.i + 0x7fffu + ((v.i >> 16) & 1u)) >> 16;
    return (unsigned short)r;
}

// ---------------- CSR build ----------------

__global__ __launch_bounds__(256) void zero_int_kernel(int* __restrict__ p, int n)
{
    int i = blockIdx.x * 256 + threadIdx.x;
    if (i < n) p[i] = 0;
}

__global__ __launch_bounds__(256) void count_deg_kernel(
    const int* __restrict__ row, int* __restrict__ deg, int E)
{
    int e = blockIdx.x * 256 + threadIdx.x;
    if (e < E) atomicAdd(&deg[row[e]], 1);
}

__global__ __launch_bounds__(1024) void scan_p1_kernel(
    const int* __restrict__ deg, int* __restrict__ rp,
    int* __restrict__ bsum, int n)
{
    __shared__ int wsum[16];
    int t = threadIdx.x, lane = t & 63, w = t >> 6;
    int base = blockIdx.x * 2048;
    int carry = 0;
    #pragma unroll
    for (int half = 0; half < 2; ++half) {
        int i = base + half * 1024 + t;
        int xv = (i < n) ? deg[i] : 0;
        int s = xv;
        #pragma unroll
        for (int off = 1; off < 64; off <<= 1) {
            int v = __shfl_up(s, off, 64);
            if (lane >= off) s += v;
        }
        if (lane == 63) wsum[w] = s;
        __syncthreads();
        if (w == 0 && lane < 16) {
            int ws = wsum[lane];
            #pragma unroll
            for (int off = 1; off < 16; off <<= 1) {
                int v = __shfl_up(ws, off, 64);
                if (lane >= off) ws += v;
            }
            wsum[lane] = ws;
        }
        __syncthreads();
        int wo = (w == 0) ? 0 : wsum[w - 1];
        if (i < n) rp[i + 1] = carry + wo + s;
        carry += wsum[15];
        if (half == 0) __syncthreads();
    }
    if (t == 0) bsum[blockIdx.x] = carry;
}

__global__ __launch_bounds__(64) void scan_p2_kernel(int* __restrict__ bsum, int B)
{
    int lane = threadIdx.x;
    int v = (lane < B) ? bsum[lane] : 0;
    int s = v;
    #pragma unroll
    for (int off = 1; off < 64; off <<= 1) {
        int u = __shfl_up(s, off, 64);
        if (lane >= off) s += u;
    }
    if (lane < B) bsum[lane] = s - v;
}

__global__ __launch_bounds__(1024) void scan_p3_kernel(
    const int* __restrict__ deg, int* __restrict__ rp,
    int* __restrict__ cursor, const int* __restrict__ bsum,
    float* __restrict__ dinv, float* __restrict__ cinv, int n)
{
    int boff = bsum[blockIdx.x];
    int base = blockIdx.x * 2048;
    #pragma unroll
    for (int half = 0; half < 2; ++half) {
        int i = base + half * 1024 + threadIdx.x;
        if (i < n) {
            int d = deg[i];
            int incl = rp[i + 1] + boff;
            rp[i + 1] = incl;
            cursor[i] = incl - d;
            float df = (float)d;
            dinv[i] = (d > 0) ? rsqrtf(df) : 0.0f;
            cinv[i] = 1.0f / fmaxf(df, 1.0f);
        }
    }
    if (blockIdx.x == 0 && threadIdx.x == 0) rp[0] = 0;
}

__global__ __launch_bounds__(256) void fill_csr_kernel(
    const int* __restrict__ row, const int* __restrict__ col,
    int* __restrict__ cursor, int* __restrict__ colS, int E)
{
    int e = blockIdx.x * 256 + threadIdx.x;
    if (e < E) {
        int p = atomicAdd(&cursor[row[e]], 1);
        colS[p] = col[e];
    }
}

// ---------------- prep ----------------

__global__ __launch_bounds__(256) void f32_to_bf16_kernel(
    const float* __restrict__ src, unsigned short* __restrict__ dst, int n4)
{
    int i = blockIdx.x * 256 + threadIdx.x;
    if (i >= n4) return;
    float4 v = ((const float4*)src)[i];
    ushort4 o;
    o.x = f2bf(v.x); o.y = f2bf(v.y); o.z = f2bf(v.z); o.w = f2bf(v.w);
    ((ushort4*)dst)[i] = o;
}

__global__ __launch_bounds__(256) void prep_w_kernel(
    const float* __restrict__ S1, int K1,
    const float* __restrict__ S2, int K2,
    int Nout, int Npad, unsigned short* __restrict__ dst)
{
    int Ktot = K1 + K2;
    int idx = blockIdx.x * 256 + threadIdx.x;
    if (idx >= Npad * Ktot) return;
    int n = idx / Ktot, k = idx - n * Ktot;
    float v = 0.0f;
    if (n < Nout)
        v = (k < K1) ? S1[(size_t)k * Nout + n] : S2[(size_t)(k - K1) * Nout + n];
    dst[idx] = f2bf(v);
}

// ---------------- aggregation: wave per node, multi-edge lanes ----------------

__device__ __forceinline__ void acc8(float* acc, uint4 u, float s) {
    unsigned int xs[4] = {u.x, u.y, u.z, u.w};
    #pragma unroll
    for (int p = 0; p < 4; ++p) {
        union { unsigned int i; float f; } lo, hi;
        lo.i = xs[p] << 16;
        hi.i = xs[p] & 0xffff0000u;
        acc[2 * p]     += s * lo.f;
        acc[2 * p + 1] += s * hi.f;
    }
}

template <int C, bool HAS_ES>
__global__ __launch_bounds__(256) void agg_bf16_kernel(
    const unsigned short* __restrict__ h, int ldh,
    const int* __restrict__ rp, const int* __restrict__ cols,
    const float* __restrict__ escale, const float* __restrict__ nscale,
    unsigned short* __restrict__ out, int ldo, int n)
{
    constexpr int LPE = (C == 256) ? 32 : 16;  // lanes per edge
    constexpr int EPG = 64 / LPE;              // edges per group (2 or 4)
    constexpr int UNR = 4;                     // gathers in flight per lane
    int node = blockIdx.x * 4 + (threadIdx.x >> 6);
    if (node >= n) return;
    int lane = threadIdx.x & 63;
    int grp = lane / LPE, sub = lane % LPE;
    const unsigned short* hc = h + sub * 8;

    int s = rp[node], e = rp[node + 1];
    float acc[8];
    #pragma unroll
    for (int k = 0; k < 8; ++k) acc[k] = 0.0f;

    for (int i = s; i < e; i += UNR * EPG) {
        int cc[UNR]; float sc[UNR]; uint4 uu[UNR];
        #pragma unroll
        for (int u = 0; u < UNR; ++u) {
            int ii = i + u * EPG + grp;
            bool valid = ii < e;
            int c = valid ? cols[ii] : 0;
            cc[u] = c;
            sc[u] = valid ? (HAS_ES ? escale[c] : 1.0f) : 0.0f;
        }
        #pragma unroll
        for (int u = 0; u < UNR; ++u)
            uu[u] = *(const uint4*)(hc + (size_t)cc[u] * ldh);
        #pragma unroll
        for (int u = 0; u < UNR; ++u)
            acc8(acc, uu[u], sc[u]);
    }

    #pragma unroll
    for (int k = 0; k < 8; ++k) {
        if (EPG == 4) acc[k] += __shfl_xor(acc[k], 16, 64);
        acc[k] += __shfl_xor(acc[k], 32, 64);
    }

    if (grp == 0) {
        float ns = nscale[node];
        uint4 o;
        unsigned int* op = (unsigned int*)&o;
        #pragma unroll
        for (int p = 0; p < 4; ++p) {
            unsigned short a = f2bf(acc[2 * p] * ns);
            unsigned short b = f2bf(acc[2 * p + 1] * ns);
            op[p] = (unsigned int)a | ((unsigned int)b << 16);
        }
        *(uint4*)(out + (size_t)node * ldo + sub * 8) = o;
    }
}

// ---------------- bf16 MFMA GEMM, 128x128 tile, 3-stage pipeline ------------

__device__ __forceinline__ void g2l16(const unsigned short* g, unsigned short* l) {
    __builtin_amdgcn_global_load_lds(
        (const __attribute__((address_space(1))) unsigned int*)g,
        (__attribute__((address_space(3))) unsigned int*)l, 16, 0, 0);
}

template <int EPI, bool RES_BF16, bool WF32, bool WB16>
__global__ __launch_bounds__(256) void mfma_gemm_kernel(
    const unsigned short* __restrict__ A1, int K1, int lda1,
    const unsigned short* __restrict__ A2, int K2, int lda2,
    const unsigned short* __restrict__ Bt,
    const float* __restrict__ bias,
    const void* __restrict__ res, int ldres,
    const float* __restrict__ alpha_ptr, int alpha_idx,
    float* __restrict__ outf, unsigned short* __restrict__ outb, int ldo,
    int M, int Nout)
{
    __shared__ unsigned short As[3][128 * 32];
    __shared__ unsigned short Bs[3][128 * 32];
    int t = threadIdx.x;
    int m0 = blockIdx.x * 128, n0 = blockIdx.y * 128;
    int Ktot = K1 + K2;
    int w = t >> 6, lane = t & 63;
    int wm = w & 1, wn = w >> 1;
    int q = lane >> 4, l16 = lane & 15;

    int roff = t >> 2;
    // source-side swizzle: lane fetches column block (t&3) ^ (row&3); linear
    // LDS then holds [row][col ^ (row&3)] with no per-lane destination.
    int koff = (((t & 3) ^ ((t >> 2) & 3)) * 8);

    int gmA0 = m0 + roff;       if (gmA0 >= M) gmA0 = M - 1;
    int gmA1 = m0 + 64 + roff;  if (gmA1 >= M) gmA1 = M - 1;
    int gnB0 = n0 + roff;
    int gnB1 = n0 + 64 + roff;

    const size_t a0off = (size_t)gmA0, a1off = (size_t)gmA1;

    f32x4 acc[4][4];
    #pragma unroll
    for (int i = 0; i < 4; ++i)
        #pragma unroll
        for (int j = 0; j < 4; ++j)
            #pragma unroll
            for (int r = 0; r < 4; ++r) acc[i][j][r] = 0.0f;

    const int KC = Ktot >> 5;

    auto issue = [&](int kc, int p) {
        int k0 = kc * 32;
        const unsigned short* Ap; int lda, kk;
        if (k0 < K1) { Ap = A1; lda = lda1; kk = k0; }
        else         { Ap = A2; lda = lda2; kk = k0 - K1; }
        g2l16(Ap + a0off * lda + kk + koff, &As[p][w * 512]);
        g2l16(Ap + a1off * lda + kk + koff, &As[p][2048 + w * 512]);
        g2l16(Bt + (size_t)gnB0 * Ktot + k0 + koff, &Bs[p][w * 512]);
        g2l16(Bt + (size_t)gnB1 * Ktot + k0 + koff, &Bs[p][2048 + w * 512]);
    };

    // matching read-side swizzle: (row & 3) == (l16 & 3) for all fragments
    const int cq = (q ^ (l16 & 3)) * 8;
    const int rbA = (wm * 64 + l16) * 32 + cq;
    const int rbB = (wn * 64 + l16) * 32 + cq;

    issue(0, 0);
    if (KC > 1) issue(1, 1);
    if (KC > 2) issue(2, 2);

    int p = 0;
    for (int kc = 0; kc < KC; ++kc) {
        int rem = KC - 1 - kc;   // chunks issued after kc (capped at 2)
        if (rem >= 2)      asm volatile("s_waitcnt vmcnt(8)" ::: "memory");
        else if (rem == 1) asm volatile("s_waitcnt vmcnt(4)" ::: "memory");
        else               asm volatile("s_waitcnt vmcnt(0)" ::: "memory");
        __builtin_amdgcn_s_barrier();      // B1: chunk-kc loads visible everywhere
        asm volatile("" ::: "memory");

        bf16x8 af[4], bfr[4];
        #pragma unroll
        for (int i = 0; i < 4; ++i)
            af[i] = *(const bf16x8*)&As[p][rbA + i * 16 * 32];
        #pragma unroll
        for (int j = 0; j < 4; ++j)
            bfr[j] = *(const bf16x8*)&Bs[p][rbB + j * 16 * 32];

        asm volatile("s_waitcnt lgkmcnt(0)" ::: "memory");
        __builtin_amdgcn_s_barrier();      // B2: all waves done reading buf p
        asm volatile("" ::: "memory");
        if (kc + 3 < KC) issue(kc + 3, p);

        __builtin_amdgcn_s_setprio(1);
        #pragma unroll
        for (int i = 0; i < 4; ++i)
            #pragma unroll
            for (int j = 0; j < 4; ++j)
                acc[i][j] = __builtin_amdgcn_mfma_f32_16x16x32_bf16(
                    af[i], bfr[j], acc[i][j], 0, 0, 0);
        __builtin_amdgcn_s_setprio(0);

        p = (p == 2) ? 0 : p + 1;
    }

    float alpha = 0.0f;
    if (EPI == 2) alpha = alpha_ptr[alpha_idx];
    #pragma unroll
    for (int i = 0; i < 4; ++i) {
        #pragma unroll
        for (int j = 0; j < 4; ++j) {
            int n = n0 + wn * 64 + j * 16 + l16;
            if (n >= Nout) continue;
            float bv = bias[n];
            #pragma unroll
            for (int r = 0; r < 4; ++r) {
                int m = m0 + wm * 64 + i * 16 + q * 4 + r;
                if (m >= M) continue;
                float v = acc[i][j][r] + bv;
                if (EPI == 1) v = fmaxf(v, 0.0f);
                if (EPI == 2) {
                    float r0 = RES_BF16
                        ? bf2f(((const unsigned short*)res)[(size_t)m * ldres + n])
                        : ((const float*)res)[(size_t)m * ldres + n];
                    v = r0 + alpha * v;
                }
                if (WF32) outf[(size_t)m * ldo + n] = v;
                if (WB16) outb[(size_t)m * ldo + n] = f2bf(v);
            }
        }
    }
}

// ---------------------------------------------------------------------------

extern "C" void kernel_launch(void* const* d_in, const int* in_sizes, int n_in,
                              void* d_out, int out_size, void* d_ws, size_t ws_size,
                              hipStream_t stream)
{
    const float* x      = (const float*)d_in[0];
    const int*   ei     = (const int*)d_in[1];
    const float* alpha  = (const float*)d_in[2];
    const float* W0     = (const float*)d_in[3];
    const float* b0     = (const float*)d_in[4];
    const float* W1     = (const float*)d_in[5];
    const float* R1     = (const float*)d_in[6];
    const float* b1     = (const float*)d_in[7];
    const float* W2     = (const float*)d_in[8];
    const float* R2     = (const float*)d_in[9];
    const float* b2     = (const float*)d_in[10];
    const float* W3     = (const float*)d_in[11];
    const float* b3     = (const float*)d_in[12];
    const float* W4     = (const float*)d_in[13];
    const float* R4     = (const float*)d_in[14];
    const float* b4     = (const float*)d_in[15];

    const int N = in_sizes[0] / 128;
    const int E = in_sizes[1] / 2;
    const int* row = ei;
    const int* col = ei + E;

    size_t off = 0;
    auto alloc = [&](size_t bytes) -> void* {
        void* p = (char*)d_ws + off;
        off += (bytes + 255) & ~(size_t)255;
        return p;
    };
    int*   deg    = (int*)alloc((size_t)N * 4);
    int*   rp     = (int*)alloc((size_t)(N + 1) * 4);
    int*   cursor = (int*)alloc((size_t)N * 4);
    int*   colS   = (int*)alloc((size_t)E * 4);
    int*   bsum   = (int*)alloc((size_t)64 * 4);
    float* dinv   = (float*)alloc((size_t)N * 4);
    float* cinv   = (float*)alloc((size_t)N * 4);
    unsigned short* Wt0 = (unsigned short*)alloc((size_t)128 * 128 * 2);
    unsigned short* Wt1 = (unsigned short*)alloc((size_t)256 * 256 * 2);
    unsigned short* Wt2 = (unsigned short*)alloc((size_t)256 * 512 * 2);
    unsigned short* Wt3 = (unsigned short*)alloc((size_t)256 * 256 * 2);
    unsigned short* Wt4 = (unsigned short*)alloc((size_t)128 * 512 * 2);
    unsigned short* Xb  = (unsigned short*)alloc((size_t)N * 128 * 2);
    unsigned short* Gb  = (unsigned short*)alloc((size_t)N * 256 * 2);
    unsigned short* Pb  = (unsigned short*)alloc((size_t)N * 256 * 2);
    unsigned short* Ab  = (unsigned short*)alloc((size_t)N * 256 * 2);
    unsigned short* Hb  = Xb;  // alias: Xb only read by L0 agg before Hb written
    (void)ws_size;

    // ---- CSR build ----
    const int SB = (N + 2047) / 2048;
    zero_int_kernel<<<(N + 255) / 256, 256, 0, stream>>>(deg, N);
    count_deg_kernel<<<(E + 255) / 256, 256, 0, stream>>>(row, deg, E);
    scan_p1_kernel<<<SB, 1024, 0, stream>>>(deg, rp, bsum, N);
    scan_p2_kernel<<<1, 64, 0, stream>>>(bsum, SB);
    scan_p3_kernel<<<SB, 1024, 0, stream>>>(deg, rp, cursor, bsum, dinv, cinv, N);
    fill_csr_kernel<<<(E + 255) / 256, 256, 0, stream>>>(row, col, cursor, colS, E);

    // ---- prep ----
    f32_to_bf16_kernel<<<(N * 32 + 255) / 256, 256, 0, stream>>>(x, Xb, N * 32);
    prep_w_kernel<<<(128 * 128 + 255) / 256, 256, 0, stream>>>(W0, 128, nullptr, 0, 128, 128, Wt0);
    prep_w_kernel<<<(256 * 256 + 255) / 256, 256, 0, stream>>>(W1, 128, R1, 128, 256, 256, Wt1);
    prep_w_kernel<<<(256 * 512 + 255) / 256, 256, 0, stream>>>(W2, 256, R2, 256, 256, 256, Wt2);
    prep_w_kernel<<<(256 * 256 + 255) / 256, 256, 0, stream>>>(W3, 256, nullptr, 0, 256, 256, Wt3);
    prep_w_kernel<<<(128 * 512 + 255) / 256, 256, 0, stream>>>(W4, 256, R4, 256, 112, 128, Wt4);

    dim3 aggGrid((N + 3) / 4);
    dim3 g1((N + 127) / 128, 1), g2((N + 127) / 128, 2);

    // ---- L0 (GCN): Hb = bf16( x + a0*(gcn_agg(x)@W0 + b0) ) ----
    agg_bf16_kernel<128, true><<<aggGrid, 256, 0, stream>>>(Xb, 128, rp, colS, dinv, dinv, Ab, 128, N);
    mfma_gemm_kernel<2, false, false, true><<<g1, 256, 0, stream>>>(
        Ab, 128, 128, nullptr, 0, 0, Wt0, b0, x, 128, alpha, 0,
        nullptr, Hb, 128, N, 128);

    // ---- L1 (SAGE 128->256): Gb = relu([mean(Hb)|Hb]@[W1;R1]+b1) ----
    agg_bf16_kernel<128, false><<<aggGrid, 256, 0, stream>>>(Hb, 128, rp, colS, nullptr, cinv, Ab, 128, N);
    mfma_gemm_kernel<1, false, false, true><<<g2, 256, 0, stream>>>(
        Ab, 128, 128, Hb, 128, 128, Wt1, b1, nullptr, 0, nullptr, 0,
        nullptr, Gb, 256, N, 256);

    // ---- L2 (SAGE 256->256): Pb = relu([mean(Gb)|Gb]@[W2;R2]+b2) ----
    agg_bf16_kernel<256, false><<<aggGrid, 256, 0, stream>>>(Gb, 256, rp, colS, nullptr, cinv, Ab, 256, N);
    mfma_gemm_kernel<1, false, false, true><<<g2, 256, 0, stream>>>(
        Ab, 256, 256, Gb, 256, 256, Wt2, b2, nullptr, 0, nullptr, 0,
        nullptr, Pb, 256, N, 256);

    // ---- L3 (GCN): Gb = Pb + a3*(gcn_agg(Pb)@W3 + b3) ----
    agg_bf16_kernel<256, true><<<aggGrid, 256, 0, stream>>>(Pb, 256, rp, colS, dinv, dinv, Ab, 256, N);
    mfma_gemm_kernel<2, true, false, true><<<g2, 256, 0, stream>>>(
        Ab, 256, 256, nullptr, 0, 0, Wt3, b3, Pb, 256, alpha, 3,
        nullptr, Gb, 256, N, 256);

    // ---- L4 (SAGE 256->112): d_out = [mean(Gb)|Gb]@[W4;R4]+b4 (fp32) ----
    agg_bf16_kernel<256, false><<<aggGrid, 256, 0, stream>>>(Gb, 256, rp, colS, nullptr, cinv, Ab, 256, N);
    mfma_gemm_kernel<0, false, true, false><<<g1, 256, 0, stream>>>(
        Ab, 256, 256, Gb, 256, 256, Wt4, b4, nullptr, 0, nullptr, 0,
        (float*)d_out, nullptr, 112, N, 112);
}

// Round 4
// 727.339 us; speedup vs baseline: 1.0688x; 1.0536x over previous
//
#include <hip/hip_runtime.h>

// ---------------------------------------------------------------------------
// SAGE_Re GNN forward, R8b (identical to R8; R8 bench was an infra failure,
// same as R7 -> R7b precedent).
// - GEMM: BN template param. BN=256 (512 thr, 8 waves) merges both N-halves
//   into one block -> A panel staged ONCE (halves FETCH for L1/L2/L3).
//   2-stage LDS, prefetch distance 2 (issue kc+2 after B2), counted vmcnt.
// - agg: unchanged (4 gathers in flight).
// - CSR: 3-phase multi-block scan (R5).
// ---------------------------------------------------------------------------

typedef __attribute__((ext_vector_type(8))) short bf16x8;
typedef __attribute__((ext_vector_type(4))) float f32x4;

__device__ __forceinline__ float bf2f(unsigned short u) {
    union { unsigned int i; float f; } v; v.i = ((unsigned int)u) << 16; return v.f;
}
__device__ __forceinline__ unsigned short f2bf(float f) {
    union { float f; unsigned int i; } v; v.f = f;
    unsigned int r = (v.i + 0x7fffu + ((v.i >> 16) & 1u)) >> 16;
    return (unsigned short)r;
}

// ---------------- CSR build ----------------

__global__ __launch_bounds__(256) void zero_int_kernel(int* __restrict__ p, int n)
{
    int i = blockIdx.x * 256 + threadIdx.x;
    if (i < n) p[i] = 0;
}

__global__ __launch_bounds__(256) void count_deg_kernel(
    const int* __restrict__ row, int* __restrict__ deg, int E)
{
    int e = blockIdx.x * 256 + threadIdx.x;
    if (e < E) atomicAdd(&deg[row[e]], 1);
}

__global__ __launch_bounds__(1024) void scan_p1_kernel(
    const int* __restrict__ deg, int* __restrict__ rp,
    int* __restrict__ bsum, int n)
{
    __shared__ int wsum[16];
    int t = threadIdx.x, lane = t & 63, w = t >> 6;
    int base = blockIdx.x * 2048;
    int carry = 0;
    #pragma unroll
    for (int half = 0; half < 2; ++half) {
        int i = base + half * 1024 + t;
        int xv = (i < n) ? deg[i] : 0;
        int s = xv;
        #pragma unroll
        for (int off = 1; off < 64; off <<= 1) {
            int v = __shfl_up(s, off, 64);
            if (lane >= off) s += v;
        }
        if (lane == 63) wsum[w] = s;
        __syncthreads();
        if (w == 0 && lane < 16) {
            int ws = wsum[lane];
            #pragma unroll
            for (int off = 1; off < 16; off <<= 1) {
                int v = __shfl_up(ws, off, 64);
                if (lane >= off) ws += v;
            }
            wsum[lane] = ws;
        }
        __syncthreads();
        int wo = (w == 0) ? 0 : wsum[w - 1];
        if (i < n) rp[i + 1] = carry + wo + s;
        carry += wsum[15];
        if (half == 0) __syncthreads();
    }
    if (t == 0) bsum[blockIdx.x] = carry;
}

__global__ __launch_bounds__(64) void scan_p2_kernel(int* __restrict__ bsum, int B)
{
    int lane = threadIdx.x;
    int v = (lane < B) ? bsum[lane] : 0;
    int s = v;
    #pragma unroll
    for (int off = 1; off < 64; off <<= 1) {
        int u = __shfl_up(s, off, 64);
        if (lane >= off) s += u;
    }
    if (lane < B) bsum[lane] = s - v;
}

__global__ __launch_bounds__(1024) void scan_p3_kernel(
    const int* __restrict__ deg, int* __restrict__ rp,
    int* __restrict__ cursor, const int* __restrict__ bsum,
    float* __restrict__ dinv, float* __restrict__ cinv, int n)
{
    int boff = bsum[blockIdx.x];
    int base = blockIdx.x * 2048;
    #pragma unroll
    for (int half = 0; half < 2; ++half) {
        int i = base + half * 1024 + threadIdx.x;
        if (i < n) {
            int d = deg[i];
            int incl = rp[i + 1] + boff;
            rp[i + 1] = incl;
            cursor[i] = incl - d;
            float df = (float)d;
            dinv[i] = (d > 0) ? rsqrtf(df) : 0.0f;
            cinv[i] = 1.0f / fmaxf(df, 1.0f);
        }
    }
    if (blockIdx.x == 0 && threadIdx.x == 0) rp[0] = 0;
}

__global__ __launch_bounds__(256) void fill_csr_kernel(
    const int* __restrict__ row, const int* __restrict__ col,
    int* __restrict__ cursor, int* __restrict__ colS, int E)
{
    int e = blockIdx.x * 256 + threadIdx.x;
    if (e < E) {
        int p = atomicAdd(&cursor[row[e]], 1);
        colS[p] = col[e];
    }
}

// ---------------- prep ----------------

__global__ __launch_bounds__(256) void f32_to_bf16_kernel(
    const float* __restrict__ src, unsigned short* __restrict__ dst, int n4)
{
    int i = blockIdx.x * 256 + threadIdx.x;
    if (i >= n4) return;
    float4 v = ((const float4*)src)[i];
    ushort4 o;
    o.x = f2bf(v.x); o.y = f2bf(v.y); o.z = f2bf(v.z); o.w = f2bf(v.w);
    ((ushort4*)dst)[i] = o;
}

__global__ __launch_bounds__(256) void prep_w_kernel(
    const float* __restrict__ S1, int K1,
    const float* __restrict__ S2, int K2,
    int Nout, int Npad, unsigned short* __restrict__ dst)
{
    int Ktot = K1 + K2;
    int idx = blockIdx.x * 256 + threadIdx.x;
    if (idx >= Npad * Ktot) return;
    int n = idx / Ktot, k = idx - n * Ktot;
    float v = 0.0f;
    if (n < Nout)
        v = (k < K1) ? S1[(size_t)k * Nout + n] : S2[(size_t)(k - K1) * Nout + n];
    dst[idx] = f2bf(v);
}

// ---------------- aggregation: wave per node, multi-edge lanes ----------------

__device__ __forceinline__ void acc8(float* acc, uint4 u, float s) {
    unsigned int xs[4] = {u.x, u.y, u.z, u.w};
    #pragma unroll
    for (int p = 0; p < 4; ++p) {
        union { unsigned int i; float f; } lo, hi;
        lo.i = xs[p] << 16;
        hi.i = xs[p] & 0xffff0000u;
        acc[2 * p]     += s * lo.f;
        acc[2 * p + 1] += s * hi.f;
    }
}

template <int C, bool HAS_ES>
__global__ __launch_bounds__(256) void agg_bf16_kernel(
    const unsigned short* __restrict__ h, int ldh,
    const int* __restrict__ rp, const int* __restrict__ cols,
    const float* __restrict__ escale, const float* __restrict__ nscale,
    unsigned short* __restrict__ out, int ldo, int n)
{
    constexpr int LPE = (C == 256) ? 32 : 16;  // lanes per edge
    constexpr int EPG = 64 / LPE;              // edges per group (2 or 4)
    constexpr int UNR = 4;                     // gathers in flight per lane
    int node = blockIdx.x * 4 + (threadIdx.x >> 6);
    if (node >= n) return;
    int lane = threadIdx.x & 63;
    int grp = lane / LPE, sub = lane % LPE;
    const unsigned short* hc = h + sub * 8;

    int s = rp[node], e = rp[node + 1];
    float acc[8];
    #pragma unroll
    for (int k = 0; k < 8; ++k) acc[k] = 0.0f;

    for (int i = s; i < e; i += UNR * EPG) {
        int cc[UNR]; float sc[UNR]; uint4 uu[UNR];
        #pragma unroll
        for (int u = 0; u < UNR; ++u) {
            int ii = i + u * EPG + grp;
            bool valid = ii < e;
            int c = valid ? cols[ii] : 0;
            cc[u] = c;
            sc[u] = valid ? (HAS_ES ? escale[c] : 1.0f) : 0.0f;
        }
        #pragma unroll
        for (int u = 0; u < UNR; ++u)
            uu[u] = *(const uint4*)(hc + (size_t)cc[u] * ldh);
        #pragma unroll
        for (int u = 0; u < UNR; ++u)
            acc8(acc, uu[u], sc[u]);
    }

    #pragma unroll
    for (int k = 0; k < 8; ++k) {
        if (EPG == 4) acc[k] += __shfl_xor(acc[k], 16, 64);
        acc[k] += __shfl_xor(acc[k], 32, 64);
    }

    if (grp == 0) {
        float ns = nscale[node];
        uint4 o;
        unsigned int* op = (unsigned int*)&o;
        #pragma unroll
        for (int p = 0; p < 4; ++p) {
            unsigned short a = f2bf(acc[2 * p] * ns);
            unsigned short b = f2bf(acc[2 * p + 1] * ns);
            op[p] = (unsigned int)a | ((unsigned int)b << 16);
        }
        *(uint4*)(out + (size_t)node * ldo + sub * 8) = o;
    }
}

// ---------------- bf16 MFMA GEMM, 128 x BN tile, 2-stage dist-2 pipeline ----

__device__ __forceinline__ void g2l16(const unsigned short* g, unsigned short* l) {
    __builtin_amdgcn_global_load_lds(
        (const __attribute__((address_space(1))) unsigned int*)g,
        (__attribute__((address_space(3))) unsigned int*)l, 16, 0, 0);
}

template <int BN, int EPI, bool RES_BF16, bool WF32, bool WB16>
__global__ __launch_bounds__(2 * BN) void mfma_gemm_kernel(
    const unsigned short* __restrict__ A1, int K1, int lda1,
    const unsigned short* __restrict__ A2, int K2, int lda2,
    const unsigned short* __restrict__ Bt,
    const float* __restrict__ bias,
    const void* __restrict__ res, int ldres,
    const float* __restrict__ alpha_ptr, int alpha_idx,
    float* __restrict__ outf, unsigned short* __restrict__ outb, int ldo,
    int M, int Nout)
{
    constexpr int WAVES = BN / 32;       // 4 (BN=128) or 8 (BN=256)
    constexpr int AI = 256 / BN;         // A-stage instrs per wave: 2 or 1
    __shared__ unsigned short As[2][128 * 32];
    __shared__ unsigned short Bs[2][BN * 32];
    int t = threadIdx.x;
    int m0 = blockIdx.x * 128, n0 = blockIdx.y * BN;
    int Ktot = K1 + K2;
    int w = t >> 6, lane = t & 63;
    int wm = w & 1, wn = w >> 1;         // wn in 0..WAVES/2-1
    int q = lane >> 4, l16 = lane & 15;

    // source-side swizzle: lane fetches 16B column-seg (lane&3)^((lane>>2)&3);
    // linear LDS then holds [row][seg ^ (row&3)] with no per-lane destination.
    int koff = (((lane & 3) ^ ((lane >> 2) & 3)) * 8);
    int rsub = lane >> 2;                // row within 16-row stripe: 0..15

    f32x4 acc[4][4];
    #pragma unroll
    for (int i = 0; i < 4; ++i)
        #pragma unroll
        for (int j = 0; j < 4; ++j)
            #pragma unroll
            for (int r = 0; r < 4; ++r) acc[i][j][r] = 0.0f;

    const int KC = Ktot >> 5;

    auto issue = [&](int kc, int p) {
        int k0 = kc * 32;
        const unsigned short* Ap; int lda, kk;
        if (k0 < K1) { Ap = A1; lda = lda1; kk = k0; }
        else         { Ap = A2; lda = lda2; kk = k0 - K1; }
        #pragma unroll
        for (int a = 0; a < AI; ++a) {
            int rb = a * 16 * WAVES + w * 16;         // LDS row base (uniform/wave)
            int gm = m0 + rb + rsub; if (gm >= M) gm = M - 1;
            g2l16(Ap + (size_t)gm * lda + kk + koff, &As[p][rb * 32]);
        }
        #pragma unroll
        for (int b = 0; b < 2; ++b) {
            int rb = b * 16 * WAVES + w * 16;
            int gn = n0 + rb + rsub;                   // < Npad by construction
            g2l16(Bt + (size_t)gn * Ktot + k0 + koff, &Bs[p][rb * 32]);
        }
    };

    // read-side swizzle: (row & 3) == (l16 & 3) for every fragment row
    const int cq = (q ^ (l16 & 3)) * 8;
    const int rbA = (wm * 64 + l16) * 32 + cq;
    const int rbB = (wn * 64 + l16) * 32 + cq;

    issue(0, 0);
    if (KC > 1) issue(1, 1);

    for (int kc = 0; kc < KC; ++kc) {
        int p = kc & 1;
        int rem = KC - 1 - kc;
        // steady state: chunks kc and kc+1 outstanding -> drain kc only.
        if (rem >= 1) {
            if constexpr (AI == 2) asm volatile("s_waitcnt vmcnt(4)" ::: "memory");
            else                   asm volatile("s_waitcnt vmcnt(3)" ::: "memory");
        } else {
            asm volatile("s_waitcnt vmcnt(0)" ::: "memory");
        }
        __builtin_amdgcn_s_barrier();      // B1: chunk-kc data visible everywhere
        asm volatile("" ::: "memory");

        bf16x8 af[4], bfr[4];
        #pragma unroll
        for (int i = 0; i < 4; ++i)
            af[i] = *(const bf16x8*)&As[p][rbA + i * 16 * 32];
        #pragma unroll
        for (int j = 0; j < 4; ++j)
            bfr[j] = *(const bf16x8*)&Bs[p][rbB + j * 16 * 32];

        asm volatile("s_waitcnt lgkmcnt(0)" ::: "memory");
        __builtin_amdgcn_s_barrier();      // B2: all waves done reading buf p
        asm volatile("" ::: "memory");
        if (kc + 2 < KC) issue(kc + 2, p); // distance-2 prefetch into freed buf

        __builtin_amdgcn_s_setprio(1);
        #pragma unroll
        for (int i = 0; i < 4; ++i)
            #pragma unroll
            for (int j = 0; j < 4; ++j)
                acc[i][j] = __builtin_amdgcn_mfma_f32_16x16x32_bf16(
                    af[i], bfr[j], acc[i][j], 0, 0, 0);
        __builtin_amdgcn_s_setprio(0);
    }

    float alpha = 0.0f;
    if (EPI == 2) alpha = alpha_ptr[alpha_idx];
    #pragma unroll
    for (int i = 0; i < 4; ++i) {
        #pragma unroll
        for (int j = 0; j < 4; ++j) {
            int n = n0 + wn * 64 + j * 16 + l16;
            if (n >= Nout) continue;
            float bv = bias[n];
            #pragma unroll
            for (int r = 0; r < 4; ++r) {
                int m = m0 + wm * 64 + i * 16 + q * 4 + r;
                if (m >= M) continue;
                float v = acc[i][j][r] + bv;
                if (EPI == 1) v = fmaxf(v, 0.0f);
                if (EPI == 2) {
                    float r0 = RES_BF16
                        ? bf2f(((const unsigned short*)res)[(size_t)m * ldres + n])
                        : ((const float*)res)[(size_t)m * ldres + n];
                    v = r0 + alpha * v;
                }
                if (WF32) outf[(size_t)m * ldo + n] = v;
                if (WB16) outb[(size_t)m * ldo + n] = f2bf(v);
            }
        }
    }
}

// ---------------------------------------------------------------------------

extern "C" void kernel_launch(void* const* d_in, const int* in_sizes, int n_in,
                              void* d_out, int out_size, void* d_ws, size_t ws_size,
                              hipStream_t stream)
{
    const float* x      = (const float*)d_in[0];
    const int*   ei     = (const int*)d_in[1];
    const float* alpha  = (const float*)d_in[2];
    const float* W0     = (const float*)d_in[3];
    const float* b0     = (const float*)d_in[4];
    const float* W1     = (const float*)d_in[5];
    const float* R1     = (const float*)d_in[6];
    const float* b1     = (const float*)d_in[7];
    const float* W2     = (const float*)d_in[8];
    const float* R2     = (const float*)d_in[9];
    const float* b2     = (const float*)d_in[10];
    const float* W3     = (const float*)d_in[11];
    const float* b3     = (const float*)d_in[12];
    const float* W4     = (const float*)d_in[13];
    const float* R4     = (const float*)d_in[14];
    const float* b4     = (const float*)d_in[15];

    const int N = in_sizes[0] / 128;
    const int E = in_sizes[1] / 2;
    const int* row = ei;
    const int* col = ei + E;

    size_t off = 0;
    auto alloc = [&](size_t bytes) -> void* {
        void* p = (char*)d_ws + off;
        off += (bytes + 255) & ~(size_t)255;
        return p;
    };
    int*   deg    = (int*)alloc((size_t)N * 4);
    int*   rp     = (int*)alloc((size_t)(N + 1) * 4);
    int*   cursor = (int*)alloc((size_t)N * 4);
    int*   colS   = (int*)alloc((size_t)E * 4);
    int*   bsum   = (int*)alloc((size_t)64 * 4);
    float* dinv   = (float*)alloc((size_t)N * 4);
    float* cinv   = (float*)alloc((size_t)N * 4);
    unsigned short* Wt0 = (unsigned short*)alloc((size_t)128 * 128 * 2);
    unsigned short* Wt1 = (unsigned short*)alloc((size_t)256 * 256 * 2);
    unsigned short* Wt2 = (unsigned short*)alloc((size_t)256 * 512 * 2);
    unsigned short* Wt3 = (unsigned short*)alloc((size_t)256 * 256 * 2);
    unsigned short* Wt4 = (unsigned short*)alloc((size_t)128 * 512 * 2);
    unsigned short* Xb  = (unsigned short*)alloc((size_t)N * 128 * 2);
    unsigned short* Gb  = (unsigned short*)alloc((size_t)N * 256 * 2);
    unsigned short* Pb  = (unsigned short*)alloc((size_t)N * 256 * 2);
    unsigned short* Ab  = (unsigned short*)alloc((size_t)N * 256 * 2);
    unsigned short* Hb  = Xb;  // alias: Xb only read by L0 agg before Hb written
    (void)ws_size;

    // ---- CSR build ----
    const int SB = (N + 2047) / 2048;
    zero_int_kernel<<<(N + 255) / 256, 256, 0, stream>>>(deg, N);
    count_deg_kernel<<<(E + 255) / 256, 256, 0, stream>>>(row, deg, E);
    scan_p1_kernel<<<SB, 1024, 0, stream>>>(deg, rp, bsum, N);
    scan_p2_kernel<<<1, 64, 0, stream>>>(bsum, SB);
    scan_p3_kernel<<<SB, 1024, 0, stream>>>(deg, rp, cursor, bsum, dinv, cinv, N);
    fill_csr_kernel<<<(E + 255) / 256, 256, 0, stream>>>(row, col, cursor, colS, E);

    // ---- prep ----
    f32_to_bf16_kernel<<<(N * 32 + 255) / 256, 256, 0, stream>>>(x, Xb, N * 32);
    prep_w_kernel<<<(128 * 128 + 255) / 256, 256, 0, stream>>>(W0, 128, nullptr, 0, 128, 128, Wt0);
    prep_w_kernel<<<(256 * 256 + 255) / 256, 256, 0, stream>>>(W1, 128, R1, 128, 256, 256, Wt1);
    prep_w_kernel<<<(256 * 512 + 255) / 256, 256, 0, stream>>>(W2, 256, R2, 256, 256, 256, Wt2);
    prep_w_kernel<<<(256 * 256 + 255) / 256, 256, 0, stream>>>(W3, 256, nullptr, 0, 256, 256, Wt3);
    prep_w_kernel<<<(128 * 512 + 255) / 256, 256, 0, stream>>>(W4, 256, R4, 256, 112, 128, Wt4);

    dim3 aggGrid((N + 3) / 4);
    dim3 g1((N + 127) / 128, 1);

    // ---- L0 (GCN): Hb = bf16( x + a0*(gcn_agg(x)@W0 + b0) ) ----
    agg_bf16_kernel<128, true><<<aggGrid, 256, 0, stream>>>(Xb, 128, rp, colS, dinv, dinv, Ab, 128, N);
    mfma_gemm_kernel<128, 2, false, false, true><<<g1, 256, 0, stream>>>(
        Ab, 128, 128, nullptr, 0, 0, Wt0, b0, x, 128, alpha, 0,
        nullptr, Hb, 128, N, 128);

    // ---- L1 (SAGE 128->256): Gb = relu([mean(Hb)|Hb]@[W1;R1]+b1) ----
    agg_bf16_kernel<128, false><<<aggGrid, 256, 0, stream>>>(Hb, 128, rp, colS, nullptr, cinv, Ab, 128, N);
    mfma_gemm_kernel<256, 1, false, false, true><<<g1, 512, 0, stream>>>(
        Ab, 128, 128, Hb, 128, 128, Wt1, b1, nullptr, 0, nullptr, 0,
        nullptr, Gb, 256, N, 256);

    // ---- L2 (SAGE 256->256): Pb = relu([mean(Gb)|Gb]@[W2;R2]+b2) ----
    agg_bf16_kernel<256, false><<<aggGrid, 256, 0, stream>>>(Gb, 256, rp, colS, nullptr, cinv, Ab, 256, N);
    mfma_gemm_kernel<256, 1, false, false, true><<<g1, 512, 0, stream>>>(
        Ab, 256, 256, Gb, 256, 256, Wt2, b2, nullptr, 0, nullptr, 0,
        nullptr, Pb, 256, N, 256);

    // ---- L3 (GCN): Gb = Pb + a3*(gcn_agg(Pb)@W3 + b3) ----
    agg_bf16_kernel<256, true><<<aggGrid, 256, 0, stream>>>(Pb, 256, rp, colS, dinv, dinv, Ab, 256, N);
    mfma_gemm_kernel<256, 2, true, false, true><<<g1, 512, 0, stream>>>(
        Ab, 256, 256, nullptr, 0, 0, Wt3, b3, Pb, 256, alpha, 3,
        nullptr, Gb, 256, N, 256);

    // ---- L4 (SAGE 256->112): d_out = [mean(Gb)|Gb]@[W4;R4]+b4 (fp32) ----
    agg_bf16_kernel<256, false><<<aggGrid, 256, 0, stream>>>(Gb, 256, rp, colS, nullptr, cinv, Ab, 256, N);
    mfma_gemm_kernel<128, 0, false, true, false><<<g1, 256, 0, stream>>>(
        Ab, 256, 256, Gb, 256, 256, Wt4, b4, nullptr, 0, nullptr, 0,
        (float*)d_out, nullptr, 112, N, 112);
}

// Round 5
// 690.921 us; speedup vs baseline: 1.1252x; 1.0527x over previous
//
#include <hip/hip_runtime.h>

// ---------------------------------------------------------------------------
// SAGE_Re GNN forward, R9.
// - dtype: ALL intermediates fp16 (was bf16). fp16 has more mantissa (10 vs
//   7 bits) and identical MFMA rate; enables v_pk_fma_f16 in the agg.
// - agg: packed half2 FMA accumulation -> ~4 VALU per 64B loaded (was ~80).
// - GEMM: swapped-operand MFMA (mfma(B,A) = C^T fragment) -> each lane holds
//   4 consecutive n at fixed m -> ushort4/float4 coalesced epilogue
//   (16 wide stores/thread instead of 64 scalar 2B stores).
// - GEMM pipeline: 2-stage LDS, prefetch distance 2, counted vmcnt (R8).
// - CSR: 3-phase multi-block scan (R5).
// ---------------------------------------------------------------------------

typedef _Float16 __attribute__((ext_vector_type(8))) f16x8;
typedef _Float16 __attribute__((ext_vector_type(2))) f16x2;
typedef __attribute__((ext_vector_type(4))) float f32x4;

__device__ __forceinline__ unsigned short f2h(float f) {
    union { _Float16 h; unsigned short u; } v; v.h = (_Float16)f; return v.u;
}
__device__ __forceinline__ float h2f(unsigned short u) {
    union { unsigned short u; _Float16 h; } v; v.u = u; return (float)v.h;
}

// ---------------- CSR build ----------------

__global__ __launch_bounds__(256) void zero_int_kernel(int* __restrict__ p, int n)
{
    int i = blockIdx.x * 256 + threadIdx.x;
    if (i < n) p[i] = 0;
}

__global__ __launch_bounds__(256) void count_deg_kernel(
    const int* __restrict__ row, int* __restrict__ deg, int E)
{
    int e = blockIdx.x * 256 + threadIdx.x;
    if (e < E) atomicAdd(&deg[row[e]], 1);
}

__global__ __launch_bounds__(1024) void scan_p1_kernel(
    const int* __restrict__ deg, int* __restrict__ rp,
    int* __restrict__ bsum, int n)
{
    __shared__ int wsum[16];
    int t = threadIdx.x, lane = t & 63, w = t >> 6;
    int base = blockIdx.x * 2048;
    int carry = 0;
    #pragma unroll
    for (int half = 0; half < 2; ++half) {
        int i = base + half * 1024 + t;
        int xv = (i < n) ? deg[i] : 0;
        int s = xv;
        #pragma unroll
        for (int off = 1; off < 64; off <<= 1) {
            int v = __shfl_up(s, off, 64);
            if (lane >= off) s += v;
        }
        if (lane == 63) wsum[w] = s;
        __syncthreads();
        if (w == 0 && lane < 16) {
            int ws = wsum[lane];
            #pragma unroll
            for (int off = 1; off < 16; off <<= 1) {
                int v = __shfl_up(ws, off, 64);
                if (lane >= off) ws += v;
            }
            wsum[lane] = ws;
        }
        __syncthreads();
        int wo = (w == 0) ? 0 : wsum[w - 1];
        if (i < n) rp[i + 1] = carry + wo + s;
        carry += wsum[15];
        if (half == 0) __syncthreads();
    }
    if (t == 0) bsum[blockIdx.x] = carry;
}

__global__ __launch_bounds__(64) void scan_p2_kernel(int* __restrict__ bsum, int B)
{
    int lane = threadIdx.x;
    int v = (lane < B) ? bsum[lane] : 0;
    int s = v;
    #pragma unroll
    for (int off = 1; off < 64; off <<= 1) {
        int u = __shfl_up(s, off, 64);
        if (lane >= off) s += u;
    }
    if (lane < B) bsum[lane] = s - v;
}

__global__ __launch_bounds__(1024) void scan_p3_kernel(
    const int* __restrict__ deg, int* __restrict__ rp,
    int* __restrict__ cursor, const int* __restrict__ bsum,
    float* __restrict__ dinv, float* __restrict__ cinv, int n)
{
    int boff = bsum[blockIdx.x];
    int base = blockIdx.x * 2048;
    #pragma unroll
    for (int half = 0; half < 2; ++half) {
        int i = base + half * 1024 + threadIdx.x;
        if (i < n) {
            int d = deg[i];
            int incl = rp[i + 1] + boff;
            rp[i + 1] = incl;
            cursor[i] = incl - d;
            float df = (float)d;
            dinv[i] = (d > 0) ? rsqrtf(df) : 0.0f;
            cinv[i] = 1.0f / fmaxf(df, 1.0f);
        }
    }
    if (blockIdx.x == 0 && threadIdx.x == 0) rp[0] = 0;
}

__global__ __launch_bounds__(256) void fill_csr_kernel(
    const int* __restrict__ row, const int* __restrict__ col,
    int* __restrict__ cursor, int* __restrict__ colS, int E)
{
    int e = blockIdx.x * 256 + threadIdx.x;
    if (e < E) {
        int p = atomicAdd(&cursor[row[e]], 1);
        colS[p] = col[e];
    }
}

// ---------------- prep ----------------

__global__ __launch_bounds__(256) void f32_to_f16_kernel(
    const float* __restrict__ src, unsigned short* __restrict__ dst, int n4)
{
    int i = blockIdx.x * 256 + threadIdx.x;
    if (i >= n4) return;
    float4 v = ((const float4*)src)[i];
    ushort4 o;
    o.x = f2h(v.x); o.y = f2h(v.y); o.z = f2h(v.z); o.w = f2h(v.w);
    ((ushort4*)dst)[i] = o;
}

__global__ __launch_bounds__(256) void prep_w_kernel(
    const float* __restrict__ S1, int K1,
    const float* __restrict__ S2, int K2,
    int Nout, int Npad, unsigned short* __restrict__ dst)
{
    int Ktot = K1 + K2;
    int idx = blockIdx.x * 256 + threadIdx.x;
    if (idx >= Npad * Ktot) return;
    int n = idx / Ktot, k = idx - n * Ktot;
    float v = 0.0f;
    if (n < Nout)
        v = (k < K1) ? S1[(size_t)k * Nout + n] : S2[(size_t)(k - K1) * Nout + n];
    dst[idx] = f2h(v);
}

// ---------------- aggregation: wave per node, packed-f16 accumulation ------

template <int C, bool HAS_ES>
__global__ __launch_bounds__(256) void agg_f16_kernel(
    const unsigned short* __restrict__ h, int ldh,
    const int* __restrict__ rp, const int* __restrict__ cols,
    const float* __restrict__ escale, const float* __restrict__ nscale,
    unsigned short* __restrict__ out, int ldo, int n)
{
    constexpr int LPE = (C == 256) ? 32 : 16;  // lanes per edge
    constexpr int EPG = 64 / LPE;              // edges per group (2 or 4)
    constexpr int UNR = 4;                     // gathers in flight per lane
    int node = blockIdx.x * 4 + (threadIdx.x >> 6);
    if (node >= n) return;
    int lane = threadIdx.x & 63;
    int grp = lane / LPE, sub = lane % LPE;
    const unsigned short* hc = h + sub * 8;

    int s = rp[node], e = rp[node + 1];
    const _Float16 hz = (_Float16)0.0f;
    f16x2 zz = { hz, hz };
    f16x2 acc2[4];
    #pragma unroll
    for (int k = 0; k < 4; ++k) acc2[k] = zz;

    for (int i = s; i < e; i += UNR * EPG) {
        int cc[UNR]; f16x2 ssv[UNR]; uint4 uu[UNR];
        #pragma unroll
        for (int u = 0; u < UNR; ++u) {
            int ii = i + u * EPG + grp;
            bool valid = ii < e;
            int c = valid ? cols[ii] : 0;
            cc[u] = c;
            float sc = valid ? (HAS_ES ? escale[c] : 1.0f) : 0.0f;
            _Float16 sh = (_Float16)sc;
            f16x2 sv = { sh, sh };
            ssv[u] = sv;
        }
        #pragma unroll
        for (int u = 0; u < UNR; ++u)
            uu[u] = *(const uint4*)(hc + (size_t)cc[u] * ldh);
        #pragma unroll
        for (int u = 0; u < UNR; ++u) {
            union { uint4 q; f16x2 hh[4]; } cv; cv.q = uu[u];
            #pragma unroll
            for (int p = 0; p < 4; ++p)
                acc2[p] += cv.hh[p] * ssv[u];       // v_pk_fma_f16
        }
    }

    #pragma unroll
    for (int k = 0; k < 4; ++k) {
        union { f16x2 h2; float f; } a, b;
        a.h2 = acc2[k];
        if (EPG == 4) { b.f = __shfl_xor(a.f, 16, 64); a.h2 = a.h2 + b.h2; }
        b.f = __shfl_xor(a.f, 32, 64); a.h2 = a.h2 + b.h2;
        acc2[k] = a.h2;
    }

    if (grp == 0) {
        _Float16 nh = (_Float16)nscale[node];
        f16x2 nn = { nh, nh };
        union { uint4 q; f16x2 hh[4]; } o;
        #pragma unroll
        for (int p = 0; p < 4; ++p) o.hh[p] = acc2[p] * nn;
        *(uint4*)(out + (size_t)node * ldo + sub * 8) = o.q;
    }
}

// ---------------- fp16 MFMA GEMM, 128 x BN tile, 2-stage dist-2 pipeline ----
// MFMA operands SWAPPED: acc = mfma(B_frag, A_frag) computes the C^T
// fragment, so each lane holds 4 consecutive n at fixed m -> wide stores.

__device__ __forceinline__ void g2l16(const unsigned short* g, unsigned short* l) {
    __builtin_amdgcn_global_load_lds(
        (const __attribute__((address_space(1))) unsigned int*)g,
        (__attribute__((address_space(3))) unsigned int*)l, 16, 0, 0);
}

template <int BN, int EPI, bool RES_F16, bool WF32, bool WB16>
__global__ __launch_bounds__(2 * BN) void mfma_gemm_kernel(
    const unsigned short* __restrict__ A1, int K1, int lda1,
    const unsigned short* __restrict__ A2, int K2, int lda2,
    const unsigned short* __restrict__ Bt,
    const float* __restrict__ bias,
    const void* __restrict__ res, int ldres,
    const float* __restrict__ alpha_ptr, int alpha_idx,
    float* __restrict__ outf, unsigned short* __restrict__ outb, int ldo,
    int M, int Nout)
{
    constexpr int WAVES = BN / 32;       // 4 (BN=128) or 8 (BN=256)
    constexpr int AI = 256 / BN;         // A-stage instrs per wave: 2 or 1
    __shared__ unsigned short As[2][128 * 32];
    __shared__ unsigned short Bs[2][BN * 32];
    int t = threadIdx.x;
    int m0 = blockIdx.x * 128, n0 = blockIdx.y * BN;
    int Ktot = K1 + K2;
    int w = t >> 6, lane = t & 63;
    int wm = w & 1, wn = w >> 1;         // wn in 0..WAVES/2-1
    int q = lane >> 4, l16 = lane & 15;

    // source-side swizzle: lane fetches 16B column-seg (lane&3)^((lane>>2)&3);
    // linear LDS then holds [row][seg ^ (row&3)] with no per-lane destination.
    int koff = (((lane & 3) ^ ((lane >> 2) & 3)) * 8);
    int rsub = lane >> 2;                // row within 16-row stripe: 0..15

    f32x4 acc[4][4];
    #pragma unroll
    for (int i = 0; i < 4; ++i)
        #pragma unroll
        for (int j = 0; j < 4; ++j)
            #pragma unroll
            for (int r = 0; r < 4; ++r) acc[i][j][r] = 0.0f;

    const int KC = Ktot >> 5;

    auto issue = [&](int kc, int p) {
        int k0 = kc * 32;
        const unsigned short* Ap; int lda, kk;
        if (k0 < K1) { Ap = A1; lda = lda1; kk = k0; }
        else         { Ap = A2; lda = lda2; kk = k0 - K1; }
        #pragma unroll
        for (int a = 0; a < AI; ++a) {
            int rb = a * 16 * WAVES + w * 16;         // LDS row base (uniform/wave)
            int gm = m0 + rb + rsub; if (gm >= M) gm = M - 1;
            g2l16(Ap + (size_t)gm * lda + kk + koff, &As[p][rb * 32]);
        }
        #pragma unroll
        for (int b = 0; b < 2; ++b) {
            int rb = b * 16 * WAVES + w * 16;
            int gn = n0 + rb + rsub;                   // < Npad by construction
            g2l16(Bt + (size_t)gn * Ktot + k0 + koff, &Bs[p][rb * 32]);
        }
    };

    // read-side swizzle: (row & 3) == (l16 & 3) for every fragment row
    const int cq = (q ^ (l16 & 3)) * 8;
    const int rbA = (wm * 64 + l16) * 32 + cq;
    const int rbB = (wn * 64 + l16) * 32 + cq;

    issue(0, 0);
    if (KC > 1) issue(1, 1);

    for (int kc = 0; kc < KC; ++kc) {
        int p = kc & 1;
        int rem = KC - 1 - kc;
        // steady state: chunks kc and kc+1 outstanding -> drain kc only.
        if (rem >= 1) {
            if constexpr (AI == 2) asm volatile("s_waitcnt vmcnt(4)" ::: "memory");
            else                   asm volatile("s_waitcnt vmcnt(3)" ::: "memory");
        } else {
            asm volatile("s_waitcnt vmcnt(0)" ::: "memory");
        }
        __builtin_amdgcn_s_barrier();      // B1: chunk-kc data visible everywhere
        asm volatile("" ::: "memory");

        f16x8 af[4], bfr[4];
        #pragma unroll
        for (int i = 0; i < 4; ++i)
            af[i] = *(const f16x8*)&As[p][rbA + i * 16 * 32];
        #pragma unroll
        for (int j = 0; j < 4; ++j)
            bfr[j] = *(const f16x8*)&Bs[p][rbB + j * 16 * 32];

        asm volatile("s_waitcnt lgkmcnt(0)" ::: "memory");
        __builtin_amdgcn_s_barrier();      // B2: all waves done reading buf p
        asm volatile("" ::: "memory");
        if (kc + 2 < KC) issue(kc + 2, p); // distance-2 prefetch into freed buf

        __builtin_amdgcn_s_setprio(1);
        #pragma unroll
        for (int i = 0; i < 4; ++i)
            #pragma unroll
            for (int j = 0; j < 4; ++j)
                acc[i][j] = __builtin_amdgcn_mfma_f32_16x16x32_f16(
                    bfr[j], af[i], acc[i][j], 0, 0, 0);   // SWAPPED -> C^T frag
        __builtin_amdgcn_s_setprio(0);
    }

    // Epilogue (swapped layout): lane (q,l16) holds, for tile (i,j),
    // m = m0 + wm*64 + i*16 + l16 (fixed), n = n0 + wn*64 + j*16 + q*4 + r.
    float alpha = 0.0f;
    if (EPI == 2) alpha = alpha_ptr[alpha_idx];
    #pragma unroll
    for (int i = 0; i < 4; ++i) {
        int m = m0 + wm * 64 + i * 16 + l16;
        if (m >= M) continue;
        #pragma unroll
        for (int j = 0; j < 4; ++j) {
            int nb = n0 + wn * 64 + j * 16 + q * 4;
            if (nb >= Nout) continue;      // Nout%16==0 -> uniform over q
            float4 bv = *(const float4*)&bias[nb];
            float v0 = acc[i][j][0] + bv.x;
            float v1 = acc[i][j][1] + bv.y;
            float v2 = acc[i][j][2] + bv.z;
            float v3 = acc[i][j][3] + bv.w;
            if (EPI == 1) {
                v0 = fmaxf(v0, 0.0f); v1 = fmaxf(v1, 0.0f);
                v2 = fmaxf(v2, 0.0f); v3 = fmaxf(v3, 0.0f);
            }
            if (EPI == 2) {
                if (RES_F16) {
                    ushort4 rr = *(const ushort4*)
                        ((const unsigned short*)res + (size_t)m * ldres + nb);
                    v0 = h2f(rr.x) + alpha * v0;
                    v1 = h2f(rr.y) + alpha * v1;
                    v2 = h2f(rr.z) + alpha * v2;
                    v3 = h2f(rr.w) + alpha * v3;
                } else {
                    float4 rr = *(const float4*)
                        ((const float*)res + (size_t)m * ldres + nb);
                    v0 = rr.x + alpha * v0;
                    v1 = rr.y + alpha * v1;
                    v2 = rr.z + alpha * v2;
                    v3 = rr.w + alpha * v3;
                }
            }
            if (WF32) {
                *(float4*)&outf[(size_t)m * ldo + nb] = make_float4(v0, v1, v2, v3);
            }
            if (WB16) {
                *(ushort4*)&outb[(size_t)m * ldo + nb] =
                    make_ushort4(f2h(v0), f2h(v1), f2h(v2), f2h(v3));
            }
        }
    }
}

// ---------------------------------------------------------------------------

extern "C" void kernel_launch(void* const* d_in, const int* in_sizes, int n_in,
                              void* d_out, int out_size, void* d_ws, size_t ws_size,
                              hipStream_t stream)
{
    const float* x      = (const float*)d_in[0];
    const int*   ei     = (const int*)d_in[1];
    const float* alpha  = (const float*)d_in[2];
    const float* W0     = (const float*)d_in[3];
    const float* b0     = (const float*)d_in[4];
    const float* W1     = (const float*)d_in[5];
    const float* R1     = (const float*)d_in[6];
    const float* b1     = (const float*)d_in[7];
    const float* W2     = (const float*)d_in[8];
    const float* R2     = (const float*)d_in[9];
    const float* b2     = (const float*)d_in[10];
    const float* W3     = (const float*)d_in[11];
    const float* b3     = (const float*)d_in[12];
    const float* W4     = (const float*)d_in[13];
    const float* R4     = (const float*)d_in[14];
    const float* b4     = (const float*)d_in[15];

    const int N = in_sizes[0] / 128;
    const int E = in_sizes[1] / 2;
    const int* row = ei;
    const int* col = ei + E;

    size_t off = 0;
    auto alloc = [&](size_t bytes) -> void* {
        void* p = (char*)d_ws + off;
        off += (bytes + 255) & ~(size_t)255;
        return p;
    };
    int*   deg    = (int*)alloc((size_t)N * 4);
    int*   rp     = (int*)alloc((size_t)(N + 1) * 4);
    int*   cursor = (int*)alloc((size_t)N * 4);
    int*   colS   = (int*)alloc((size_t)E * 4);
    int*   bsum   = (int*)alloc((size_t)64 * 4);
    float* dinv   = (float*)alloc((size_t)N * 4);
    float* cinv   = (float*)alloc((size_t)N * 4);
    unsigned short* Wt0 = (unsigned short*)alloc((size_t)128 * 128 * 2);
    unsigned short* Wt1 = (unsigned short*)alloc((size_t)256 * 256 * 2);
    unsigned short* Wt2 = (unsigned short*)alloc((size_t)256 * 512 * 2);
    unsigned short* Wt3 = (unsigned short*)alloc((size_t)256 * 256 * 2);
    unsigned short* Wt4 = (unsigned short*)alloc((size_t)128 * 512 * 2);
    unsigned short* Xb  = (unsigned short*)alloc((size_t)N * 128 * 2);
    unsigned short* Gb  = (unsigned short*)alloc((size_t)N * 256 * 2);
    unsigned short* Pb  = (unsigned short*)alloc((size_t)N * 256 * 2);
    unsigned short* Ab  = (unsigned short*)alloc((size_t)N * 256 * 2);
    unsigned short* Hb  = Xb;  // alias: Xb only read by L0 agg before Hb written
    (void)ws_size;

    // ---- CSR build ----
    const int SB = (N + 2047) / 2048;
    zero_int_kernel<<<(N + 255) / 256, 256, 0, stream>>>(deg, N);
    count_deg_kernel<<<(E + 255) / 256, 256, 0, stream>>>(row, deg, E);
    scan_p1_kernel<<<SB, 1024, 0, stream>>>(deg, rp, bsum, N);
    scan_p2_kernel<<<1, 64, 0, stream>>>(bsum, SB);
    scan_p3_kernel<<<SB, 1024, 0, stream>>>(deg, rp, cursor, bsum, dinv, cinv, N);
    fill_csr_kernel<<<(E + 255) / 256, 256, 0, stream>>>(row, col, cursor, colS, E);

    // ---- prep ----
    f32_to_f16_kernel<<<(N * 32 + 255) / 256, 256, 0, stream>>>(x, Xb, N * 32);
    prep_w_kernel<<<(128 * 128 + 255) / 256, 256, 0, stream>>>(W0, 128, nullptr, 0, 128, 128, Wt0);
    prep_w_kernel<<<(256 * 256 + 255) / 256, 256, 0, stream>>>(W1, 128, R1, 128, 256, 256, Wt1);
    prep_w_kernel<<<(256 * 512 + 255) / 256, 256, 0, stream>>>(W2, 256, R2, 256, 256, 256, Wt2);
    prep_w_kernel<<<(256 * 256 + 255) / 256, 256, 0, stream>>>(W3, 256, nullptr, 0, 256, 256, Wt3);
    prep_w_kernel<<<(128 * 512 + 255) / 256, 256, 0, stream>>>(W4, 256, R4, 256, 112, 128, Wt4);

    dim3 aggGrid((N + 3) / 4);
    dim3 g1((N + 127) / 128, 1);

    // ---- L0 (GCN): Hb = f16( x + a0*(gcn_agg(x)@W0 + b0) ) ----
    agg_f16_kernel<128, true><<<aggGrid, 256, 0, stream>>>(Xb, 128, rp, colS, dinv, dinv, Ab, 128, N);
    mfma_gemm_kernel<128, 2, false, false, true><<<g1, 256, 0, stream>>>(
        Ab, 128, 128, nullptr, 0, 0, Wt0, b0, x, 128, alpha, 0,
        nullptr, Hb, 128, N, 128);

    // ---- L1 (SAGE 128->256): Gb = relu([mean(Hb)|Hb]@[W1;R1]+b1) ----
    agg_f16_kernel<128, false><<<aggGrid, 256, 0, stream>>>(Hb, 128, rp, colS, nullptr, cinv, Ab, 128, N);
    mfma_gemm_kernel<256, 1, false, false, true><<<g1, 512, 0, stream>>>(
        Ab, 128, 128, Hb, 128, 128, Wt1, b1, nullptr, 0, nullptr, 0,
        nullptr, Gb, 256, N, 256);

    // ---- L2 (SAGE 256->256): Pb = relu([mean(Gb)|Gb]@[W2;R2]+b2) ----
    agg_f16_kernel<256, false><<<aggGrid, 256, 0, stream>>>(Gb, 256, rp, colS, nullptr, cinv, Ab, 256, N);
    mfma_gemm_kernel<256, 1, false, false, true><<<g1, 512, 0, stream>>>(
        Ab, 256, 256, Gb, 256, 256, Wt2, b2, nullptr, 0, nullptr, 0,
        nullptr, Pb, 256, N, 256);

    // ---- L3 (GCN): Gb = Pb + a3*(gcn_agg(Pb)@W3 + b3) ----
    agg_f16_kernel<256, true><<<aggGrid, 256, 0, stream>>>(Pb, 256, rp, colS, dinv, dinv, Ab, 256, N);
    mfma_gemm_kernel<256, 2, true, false, true><<<g1, 512, 0, stream>>>(
        Ab, 256, 256, nullptr, 0, 0, Wt3, b3, Pb, 256, alpha, 3,
        nullptr, Gb, 256, N, 256);

    // ---- L4 (SAGE 256->112): d_out = [mean(Gb)|Gb]@[W4;R4]+b4 (fp32) ----
    agg_f16_kernel<256, false><<<aggGrid, 256, 0, stream>>>(Gb, 256, rp, colS, nullptr, cinv, Ab, 256, N);
    mfma_gemm_kernel<128, 0, false, true, false><<<g1, 256, 0, stream>>>(
        Ab, 256, 256, Gb, 256, 256, Wt4, b4, nullptr, 0, nullptr, 0,
        (float*)d_out, nullptr, 112, N, 112);
}

// Round 6
// 678.082 us; speedup vs baseline: 1.1465x; 1.0189x over previous
//
#include <hip/hip_runtime.h>

// ---------------------------------------------------------------------------
// SAGE_Re GNN forward, R10.
// - agg: PREDICATED gathers (exec-masked lanes issue no request -> no more
//   row-0 waste slots), UNR=6 outstanding loads/lane, one pass covers
//   deg <= 12 (C=256) / 24 (C=128).
// - L4 restructured via agg/GEMM commutation: mean(Gb)@W4 = cinv*A*(Gb@W4).
//   One dual-output GEMM (T=Gb@W4 fp16 ld128; U=Gb@R4+b4 fp32 -> d_out),
//   then a 128-ch agg that RMWs d_out += cinv*A*T. Halves L4 gather bytes.
// - GEMM: fp16 MFMA, swapped-operand C^T fragment, wide epilogue (R9);
//   2-stage LDS, dist-2 prefetch, counted vmcnt (R8).
// - CSR: 3-phase multi-block scan (R5).
// ---------------------------------------------------------------------------

typedef _Float16 __attribute__((ext_vector_type(8))) f16x8;
typedef _Float16 __attribute__((ext_vector_type(2))) f16x2;
typedef __attribute__((ext_vector_type(4))) float f32x4;

__device__ __forceinline__ unsigned short f2h(float f) {
    union { _Float16 h; unsigned short u; } v; v.h = (_Float16)f; return v.u;
}
__device__ __forceinline__ float h2f(unsigned short u) {
    union { unsigned short u; _Float16 h; } v; v.u = u; return (float)v.h;
}

// ---------------- CSR build ----------------

__global__ __launch_bounds__(256) void zero_int_kernel(int* __restrict__ p, int n)
{
    int i = blockIdx.x * 256 + threadIdx.x;
    if (i < n) p[i] = 0;
}

__global__ __launch_bounds__(256) void count_deg_kernel(
    const int* __restrict__ row, int* __restrict__ deg, int E)
{
    int e = blockIdx.x * 256 + threadIdx.x;
    if (e < E) atomicAdd(&deg[row[e]], 1);
}

__global__ __launch_bounds__(1024) void scan_p1_kernel(
    const int* __restrict__ deg, int* __restrict__ rp,
    int* __restrict__ bsum, int n)
{
    __shared__ int wsum[16];
    int t = threadIdx.x, lane = t & 63, w = t >> 6;
    int base = blockIdx.x * 2048;
    int carry = 0;
    #pragma unroll
    for (int half = 0; half < 2; ++half) {
        int i = base + half * 1024 + t;
        int xv = (i < n) ? deg[i] : 0;
        int s = xv;
        #pragma unroll
        for (int off = 1; off < 64; off <<= 1) {
            int v = __shfl_up(s, off, 64);
            if (lane >= off) s += v;
        }
        if (lane == 63) wsum[w] = s;
        __syncthreads();
        if (w == 0 && lane < 16) {
            int ws = wsum[lane];
            #pragma unroll
            for (int off = 1; off < 16; off <<= 1) {
                int v = __shfl_up(ws, off, 64);
                if (lane >= off) ws += v;
            }
            wsum[lane] = ws;
        }
        __syncthreads();
        int wo = (w == 0) ? 0 : wsum[w - 1];
        if (i < n) rp[i + 1] = carry + wo + s;
        carry += wsum[15];
        if (half == 0) __syncthreads();
    }
    if (t == 0) bsum[blockIdx.x] = carry;
}

__global__ __launch_bounds__(64) void scan_p2_kernel(int* __restrict__ bsum, int B)
{
    int lane = threadIdx.x;
    int v = (lane < B) ? bsum[lane] : 0;
    int s = v;
    #pragma unroll
    for (int off = 1; off < 64; off <<= 1) {
        int u = __shfl_up(s, off, 64);
        if (lane >= off) s += u;
    }
    if (lane < B) bsum[lane] = s - v;
}

__global__ __launch_bounds__(1024) void scan_p3_kernel(
    const int* __restrict__ deg, int* __restrict__ rp,
    int* __restrict__ cursor, const int* __restrict__ bsum,
    float* __restrict__ dinv, float* __restrict__ cinv, int n)
{
    int boff = bsum[blockIdx.x];
    int base = blockIdx.x * 2048;
    #pragma unroll
    for (int half = 0; half < 2; ++half) {
        int i = base + half * 1024 + threadIdx.x;
        if (i < n) {
            int d = deg[i];
            int incl = rp[i + 1] + boff;
            rp[i + 1] = incl;
            cursor[i] = incl - d;
            float df = (float)d;
            dinv[i] = (d > 0) ? rsqrtf(df) : 0.0f;
            cinv[i] = 1.0f / fmaxf(df, 1.0f);
        }
    }
    if (blockIdx.x == 0 && threadIdx.x == 0) rp[0] = 0;
}

__global__ __launch_bounds__(256) void fill_csr_kernel(
    const int* __restrict__ row, const int* __restrict__ col,
    int* __restrict__ cursor, int* __restrict__ colS, int E)
{
    int e = blockIdx.x * 256 + threadIdx.x;
    if (e < E) {
        int p = atomicAdd(&cursor[row[e]], 1);
        colS[p] = col[e];
    }
}

// ---------------- prep ----------------

__global__ __launch_bounds__(256) void f32_to_f16_kernel(
    const float* __restrict__ src, unsigned short* __restrict__ dst, int n4)
{
    int i = blockIdx.x * 256 + threadIdx.x;
    if (i >= n4) return;
    float4 v = ((const float4*)src)[i];
    ushort4 o;
    o.x = f2h(v.x); o.y = f2h(v.y); o.z = f2h(v.z); o.w = f2h(v.w);
    ((ushort4*)dst)[i] = o;
}

__global__ __launch_bounds__(256) void prep_w_kernel(
    const float* __restrict__ S1, int K1,
    const float* __restrict__ S2, int K2,
    int Nout, int Npad, unsigned short* __restrict__ dst)
{
    int Ktot = K1 + K2;
    int idx = blockIdx.x * 256 + threadIdx.x;
    if (idx >= Npad * Ktot) return;
    int n = idx / Ktot, k = idx - n * Ktot;
    float v = 0.0f;
    if (n < Nout)
        v = (k < K1) ? S1[(size_t)k * Nout + n] : S2[(size_t)(k - K1) * Nout + n];
    dst[idx] = f2h(v);
}

// L4 weight prep: dst is 256 rows (n) x 256 cols (k):
//   n<112 -> W4[:,n] ; 112<=n<224 -> R4[:,n-112] ; else 0.
__global__ __launch_bounds__(256) void prep_w2_kernel(
    const float* __restrict__ W4, const float* __restrict__ R4,
    unsigned short* __restrict__ dst)
{
    int idx = blockIdx.x * 256 + threadIdx.x;   // 256*256 total
    int nrow = idx >> 8, k = idx & 255;
    float v = 0.0f;
    if (nrow < 112)      v = W4[(size_t)k * 112 + nrow];
    else if (nrow < 224) v = R4[(size_t)k * 112 + (nrow - 112)];
    dst[idx] = f2h(v);
}

__global__ __launch_bounds__(256) void prep_biasP_kernel(
    const float* __restrict__ b4, float* __restrict__ biasP)
{
    int i = threadIdx.x;   // 256
    biasP[i] = (i >= 112 && i < 224) ? b4[i - 112] : 0.0f;
}

// ---------------- aggregation: wave per node, predicated gathers ------------
// OUT_MODE 0: out f16 (acc * nscale).   OUT_MODE 1: fout (f32, width 112)
//   += nscale * acc   (RMW of the GEMM-produced U term).

template <int C, bool HAS_ES, int OUT_MODE>
__global__ __launch_bounds__(256) void agg_f16_kernel(
    const unsigned short* __restrict__ h, int ldh,
    const int* __restrict__ rp, const int* __restrict__ cols,
    const float* __restrict__ escale, const float* __restrict__ nscale,
    unsigned short* __restrict__ out, int ldo,
    float* __restrict__ fout, int ldof, int n)
{
    constexpr int LPE = (C == 256) ? 32 : 16;  // lanes per edge
    constexpr int EPG = 64 / LPE;              // edges per group (2 or 4)
    constexpr int UNR = 6;                     // predicated gathers in flight
    int node = blockIdx.x * 4 + (threadIdx.x >> 6);
    if (node >= n) return;
    int lane = threadIdx.x & 63;
    int grp = lane / LPE, sub = lane % LPE;
    const unsigned short* hc = h + sub * 8;

    int s = rp[node], e = rp[node + 1];
    const _Float16 hz = (_Float16)0.0f;
    f16x2 zz = { hz, hz };
    f16x2 acc2[4];
    #pragma unroll
    for (int k = 0; k < 4; ++k) acc2[k] = zz;

    for (int i = s; i < e; i += UNR * EPG) {
        bool vv[UNR]; f16x2 ssv[UNR]; uint4 uu[UNR]; int cc[UNR];
        #pragma unroll
        for (int u = 0; u < UNR; ++u) {
            int ii = i + u * EPG + grp;
            bool valid = ii < e;
            vv[u] = valid;
            int c = cols[valid ? ii : s];
            cc[u] = c;
            float sc = valid ? (HAS_ES ? escale[c] : 1.0f) : 0.0f;
            _Float16 sh = (_Float16)sc;
            f16x2 sv = { sh, sh };
            ssv[u] = sv;
        }
        #pragma unroll
        for (int u = 0; u < UNR; ++u) {
            uint4 z = { 0u, 0u, 0u, 0u };
            uu[u] = z;
            if (vv[u])    // exec-masked: invalid lanes issue NO request
                uu[u] = *(const uint4*)(hc + (size_t)cc[u] * ldh);
        }
        #pragma unroll
        for (int u = 0; u < UNR; ++u) {
            union { uint4 q; f16x2 hh[4]; } cv; cv.q = uu[u];
            #pragma unroll
            for (int p = 0; p < 4; ++p)
                acc2[p] += cv.hh[p] * ssv[u];       // v_pk_fma_f16
        }
    }

    #pragma unroll
    for (int k = 0; k < 4; ++k) {
        union { f16x2 h2; float f; } a, b;
        a.h2 = acc2[k];
        if (EPG == 4) { b.f = __shfl_xor(a.f, 16, 64); a.h2 = a.h2 + b.h2; }
        b.f = __shfl_xor(a.f, 32, 64); a.h2 = a.h2 + b.h2;
        acc2[k] = a.h2;
    }

    if (OUT_MODE == 0) {
        if (grp == 0) {
            _Float16 nh = (_Float16)nscale[node];
            f16x2 nn = { nh, nh };
            union { uint4 q; f16x2 hh[4]; } o;
            #pragma unroll
            for (int p = 0; p < 4; ++p) o.hh[p] = acc2[p] * nn;
            *(uint4*)(out + (size_t)node * ldo + sub * 8) = o.q;
        }
    } else {
        // fout[node][sub*8 .. +7] += nscale * acc  (cols >= 112 skipped)
        if (grp == 0 && sub < 14) {
            float cs = nscale[node];
            float* U = fout + (size_t)node * ldof + sub * 8;
            float4 u0 = *(float4*)U;
            float4 u1 = *(float4*)(U + 4);
            u0.x += cs * (float)acc2[0][0];
            u0.y += cs * (float)acc2[0][1];
            u0.z += cs * (float)acc2[1][0];
            u0.w += cs * (float)acc2[1][1];
            u1.x += cs * (float)acc2[2][0];
            u1.y += cs * (float)acc2[2][1];
            u1.z += cs * (float)acc2[3][0];
            u1.w += cs * (float)acc2[3][1];
            *(float4*)U = u0;
            *(float4*)(U + 4) = u1;
        }
    }
}

// ---------------- fp16 MFMA GEMM, 128 x BN tile, 2-stage dist-2 pipeline ----
// MFMA operands SWAPPED: acc = mfma(B_frag, A_frag) computes the C^T
// fragment, so each lane holds 4 consecutive n at fixed m -> wide stores.
// EPI: 0 none, 1 relu, 2 residual (res + alpha*v), 3 dual-output L4
//   (n<112 -> f16 T at outb/ldo; n>=112 -> f32 U at outf/ldres).

__device__ __forceinline__ void g2l16(const unsigned short* g, unsigned short* l) {
    __builtin_amdgcn_global_load_lds(
        (const __attribute__((address_space(1))) unsigned int*)g,
        (__attribute__((address_space(3))) unsigned int*)l, 16, 0, 0);
}

template <int BN, int EPI, bool RES_F16, bool WF32, bool WB16>
__global__ __launch_bounds__(2 * BN) void mfma_gemm_kernel(
    const unsigned short* __restrict__ A1, int K1, int lda1,
    const unsigned short* __restrict__ A2, int K2, int lda2,
    const unsigned short* __restrict__ Bt,
    const float* __restrict__ bias,
    const void* __restrict__ res, int ldres,
    const float* __restrict__ alpha_ptr, int alpha_idx,
    float* __restrict__ outf, unsigned short* __restrict__ outb, int ldo,
    int M, int Nout)
{
    constexpr int WAVES = BN / 32;       // 4 (BN=128) or 8 (BN=256)
    constexpr int AI = 256 / BN;         // A-stage instrs per wave: 2 or 1
    __shared__ unsigned short As[2][128 * 32];
    __shared__ unsigned short Bs[2][BN * 32];
    int t = threadIdx.x;
    int m0 = blockIdx.x * 128, n0 = blockIdx.y * BN;
    int Ktot = K1 + K2;
    int w = t >> 6, lane = t & 63;
    int wm = w & 1, wn = w >> 1;         // wn in 0..WAVES/2-1
    int q = lane >> 4, l16 = lane & 15;

    // source-side swizzle: lane fetches 16B column-seg (lane&3)^((lane>>2)&3);
    // linear LDS then holds [row][seg ^ (row&3)] with no per-lane destination.
    int koff = (((lane & 3) ^ ((lane >> 2) & 3)) * 8);
    int rsub = lane >> 2;                // row within 16-row stripe: 0..15

    f32x4 acc[4][4];
    #pragma unroll
    for (int i = 0; i < 4; ++i)
        #pragma unroll
        for (int j = 0; j < 4; ++j)
            #pragma unroll
            for (int r = 0; r < 4; ++r) acc[i][j][r] = 0.0f;

    const int KC = Ktot >> 5;

    auto issue = [&](int kc, int p) {
        int k0 = kc * 32;
        const unsigned short* Ap; int lda, kk;
        if (k0 < K1) { Ap = A1; lda = lda1; kk = k0; }
        else         { Ap = A2; lda = lda2; kk = k0 - K1; }
        #pragma unroll
        for (int a = 0; a < AI; ++a) {
            int rb = a * 16 * WAVES + w * 16;         // LDS row base (uniform/wave)
            int gm = m0 + rb + rsub; if (gm >= M) gm = M - 1;
            g2l16(Ap + (size_t)gm * lda + kk + koff, &As[p][rb * 32]);
        }
        #pragma unroll
        for (int b = 0; b < 2; ++b) {
            int rb = b * 16 * WAVES + w * 16;
            int gn = n0 + rb + rsub;                   // < Npad by construction
            g2l16(Bt + (size_t)gn * Ktot + k0 + koff, &Bs[p][rb * 32]);
        }
    };

    // read-side swizzle: (row & 3) == (l16 & 3) for every fragment row
    const int cq = (q ^ (l16 & 3)) * 8;
    const int rbA = (wm * 64 + l16) * 32 + cq;
    const int rbB = (wn * 64 + l16) * 32 + cq;

    issue(0, 0);
    if (KC > 1) issue(1, 1);

    for (int kc = 0; kc < KC; ++kc) {
        int p = kc & 1;
        int rem = KC - 1 - kc;
        // steady state: chunks kc and kc+1 outstanding -> drain kc only.
        if (rem >= 1) {
            if constexpr (AI == 2) asm volatile("s_waitcnt vmcnt(4)" ::: "memory");
            else                   asm volatile("s_waitcnt vmcnt(3)" ::: "memory");
        } else {
            asm volatile("s_waitcnt vmcnt(0)" ::: "memory");
        }
        __builtin_amdgcn_s_barrier();      // B1: chunk-kc data visible everywhere
        asm volatile("" ::: "memory");

        f16x8 af[4], bfr[4];
        #pragma unroll
        for (int i = 0; i < 4; ++i)
            af[i] = *(const f16x8*)&As[p][rbA + i * 16 * 32];
        #pragma unroll
        for (int j = 0; j < 4; ++j)
            bfr[j] = *(const f16x8*)&Bs[p][rbB + j * 16 * 32];

        asm volatile("s_waitcnt lgkmcnt(0)" ::: "memory");
        __builtin_amdgcn_s_barrier();      // B2: all waves done reading buf p
        asm volatile("" ::: "memory");
        if (kc + 2 < KC) issue(kc + 2, p); // distance-2 prefetch into freed buf

        __builtin_amdgcn_s_setprio(1);
        #pragma unroll
        for (int i = 0; i < 4; ++i)
            #pragma unroll
            for (int j = 0; j < 4; ++j)
                acc[i][j] = __builtin_amdgcn_mfma_f32_16x16x32_f16(
                    bfr[j], af[i], acc[i][j], 0, 0, 0);   // SWAPPED -> C^T frag
        __builtin_amdgcn_s_setprio(0);
    }

    // Epilogue (swapped layout): lane (q,l16) holds, for tile (i,j),
    // m = m0 + wm*64 + i*16 + l16 (fixed), n = n0 + wn*64 + j*16 + q*4 + r.
    float alpha = 0.0f;
    if (EPI == 2) alpha = alpha_ptr[alpha_idx];
    #pragma unroll
    for (int i = 0; i < 4; ++i) {
        int m = m0 + wm * 64 + i * 16 + l16;
        if (m >= M) continue;
        #pragma unroll
        for (int j = 0; j < 4; ++j) {
            int nb = n0 + wn * 64 + j * 16 + q * 4;
            if (nb >= Nout) continue;      // Nout%16==0 or 224 -> uniform over q
            float4 bv = *(const float4*)&bias[nb];
            float v0 = acc[i][j][0] + bv.x;
            float v1 = acc[i][j][1] + bv.y;
            float v2 = acc[i][j][2] + bv.z;
            float v3 = acc[i][j][3] + bv.w;
            if (EPI == 3) {
                if (nb < 112) {
                    *(ushort4*)&outb[(size_t)m * ldo + nb] =
                        make_ushort4(f2h(v0), f2h(v1), f2h(v2), f2h(v3));
                } else {
                    *(float4*)&outf[(size_t)m * ldres + (nb - 112)] =
                        make_float4(v0, v1, v2, v3);
                }
                continue;
            }
            if (EPI == 1) {
                v0 = fmaxf(v0, 0.0f); v1 = fmaxf(v1, 0.0f);
                v2 = fmaxf(v2, 0.0f); v3 = fmaxf(v3, 0.0f);
            }
            if (EPI == 2) {
                if (RES_F16) {
                    ushort4 rr = *(const ushort4*)
                        ((const unsigned short*)res + (size_t)m * ldres + nb);
                    v0 = h2f(rr.x) + alpha * v0;
                    v1 = h2f(rr.y) + alpha * v1;
                    v2 = h2f(rr.z) + alpha * v2;
                    v3 = h2f(rr.w) + alpha * v3;
                } else {
                    float4 rr = *(const float4*)
                        ((const float*)res + (size_t)m * ldres + nb);
                    v0 = rr.x + alpha * v0;
                    v1 = rr.y + alpha * v1;
                    v2 = rr.z + alpha * v2;
                    v3 = rr.w + alpha * v3;
                }
            }
            if (WF32) {
                *(float4*)&outf[(size_t)m * ldo + nb] = make_float4(v0, v1, v2, v3);
            }
            if (WB16) {
                *(ushort4*)&outb[(size_t)m * ldo + nb] =
                    make_ushort4(f2h(v0), f2h(v1), f2h(v2), f2h(v3));
            }
        }
    }
}

// ---------------------------------------------------------------------------

extern "C" void kernel_launch(void* const* d_in, const int* in_sizes, int n_in,
                              void* d_out, int out_size, void* d_ws, size_t ws_size,
                              hipStream_t stream)
{
    const float* x      = (const float*)d_in[0];
    const int*   ei     = (const int*)d_in[1];
    const float* alpha  = (const float*)d_in[2];
    const float* W0     = (const float*)d_in[3];
    const float* b0     = (const float*)d_in[4];
    const float* W1     = (const float*)d_in[5];
    const float* R1     = (const float*)d_in[6];
    const float* b1     = (const float*)d_in[7];
    const float* W2     = (const float*)d_in[8];
    const float* R2     = (const float*)d_in[9];
    const float* b2     = (const float*)d_in[10];
    const float* W3     = (const float*)d_in[11];
    const float* b3     = (const float*)d_in[12];
    const float* W4     = (const float*)d_in[13];
    const float* R4     = (const float*)d_in[14];
    const float* b4     = (const float*)d_in[15];

    const int N = in_sizes[0] / 128;
    const int E = in_sizes[1] / 2;
    const int* row = ei;
    const int* col = ei + E;

    size_t off = 0;
    auto alloc = [&](size_t bytes) -> void* {
        void* p = (char*)d_ws + off;
        off += (bytes + 255) & ~(size_t)255;
        return p;
    };
    int*   deg    = (int*)alloc((size_t)N * 4);
    int*   rp     = (int*)alloc((size_t)(N + 1) * 4);
    int*   cursor = (int*)alloc((size_t)N * 4);
    int*   colS   = (int*)alloc((size_t)E * 4);
    int*   bsum   = (int*)alloc((size_t)64 * 4);
    float* dinv   = (float*)alloc((size_t)N * 4);
    float* cinv   = (float*)alloc((size_t)N * 4);
    unsigned short* Wt0 = (unsigned short*)alloc((size_t)128 * 128 * 2);
    unsigned short* Wt1 = (unsigned short*)alloc((size_t)256 * 256 * 2);
    unsigned short* Wt2 = (unsigned short*)alloc((size_t)256 * 512 * 2);
    unsigned short* Wt3 = (unsigned short*)alloc((size_t)256 * 256 * 2);
    unsigned short* Wt4p= (unsigned short*)alloc((size_t)256 * 256 * 2);
    float* biasP  = (float*)alloc((size_t)256 * 4);
    unsigned short* Xb  = (unsigned short*)alloc((size_t)N * 128 * 2);
    unsigned short* Gb  = (unsigned short*)alloc((size_t)N * 256 * 2);
    unsigned short* Pb  = (unsigned short*)alloc((size_t)N * 256 * 2);
    unsigned short* Ab  = (unsigned short*)alloc((size_t)N * 256 * 2);
    unsigned short* Hb  = Xb;  // alias: Xb only read by L0 agg before Hb written
    (void)ws_size;

    // ---- CSR build ----
    const int SB = (N + 2047) / 2048;
    zero_int_kernel<<<(N + 255) / 256, 256, 0, stream>>>(deg, N);
    count_deg_kernel<<<(E + 255) / 256, 256, 0, stream>>>(row, deg, E);
    scan_p1_kernel<<<SB, 1024, 0, stream>>>(deg, rp, bsum, N);
    scan_p2_kernel<<<1, 64, 0, stream>>>(bsum, SB);
    scan_p3_kernel<<<SB, 1024, 0, stream>>>(deg, rp, cursor, bsum, dinv, cinv, N);
    fill_csr_kernel<<<(E + 255) / 256, 256, 0, stream>>>(row, col, cursor, colS, E);

    // ---- prep ----
    f32_to_f16_kernel<<<(N * 32 + 255) / 256, 256, 0, stream>>>(x, Xb, N * 32);
    prep_w_kernel<<<(128 * 128 + 255) / 256, 256, 0, stream>>>(W0, 128, nullptr, 0, 128, 128, Wt0);
    prep_w_kernel<<<(256 * 256 + 255) / 256, 256, 0, stream>>>(W1, 128, R1, 128, 256, 256, Wt1);
    prep_w_kernel<<<(256 * 512 + 255) / 256, 256, 0, stream>>>(W2, 256, R2, 256, 256, 256, Wt2);
    prep_w_kernel<<<(256 * 256 + 255) / 256, 256, 0, stream>>>(W3, 256, nullptr, 0, 256, 256, Wt3);
    prep_w2_kernel<<<(256 * 256) / 256, 256, 0, stream>>>(W4, R4, Wt4p);
    prep_biasP_kernel<<<1, 256, 0, stream>>>(b4, biasP);

    dim3 aggGrid((N + 3) / 4);
    dim3 g1((N + 127) / 128, 1);

    // ---- L0 (GCN): Hb = f16( x + a0*(gcn_agg(x)@W0 + b0) ) ----
    agg_f16_kernel<128, true, 0><<<aggGrid, 256, 0, stream>>>(
        Xb, 128, rp, colS, dinv, dinv, Ab, 128, nullptr, 0, N);
    mfma_gemm_kernel<128, 2, false, false, true><<<g1, 256, 0, stream>>>(
        Ab, 128, 128, nullptr, 0, 0, Wt0, b0, x, 128, alpha, 0,
        nullptr, Hb, 128, N, 128);

    // ---- L1 (SAGE 128->256): Gb = relu([mean(Hb)|Hb]@[W1;R1]+b1) ----
    agg_f16_kernel<128, false, 0><<<aggGrid, 256, 0, stream>>>(
        Hb, 128, rp, colS, nullptr, cinv, Ab, 128, nullptr, 0, N);
    mfma_gemm_kernel<256, 1, false, false, true><<<g1, 512, 0, stream>>>(
        Ab, 128, 128, Hb, 128, 128, Wt1, b1, nullptr, 0, nullptr, 0,
        nullptr, Gb, 256, N, 256);

    // ---- L2 (SAGE 256->256): Pb = relu([mean(Gb)|Gb]@[W2;R2]+b2) ----
    agg_f16_kernel<256, false, 0><<<aggGrid, 256, 0, stream>>>(
        Gb, 256, rp, colS, nullptr, cinv, Ab, 256, nullptr, 0, N);
    mfma_gemm_kernel<256, 1, false, false, true><<<g1, 512, 0, stream>>>(
        Ab, 256, 256, Gb, 256, 256, Wt2, b2, nullptr, 0, nullptr, 0,
        nullptr, Pb, 256, N, 256);

    // ---- L3 (GCN): Gb = Pb + a3*(gcn_agg(Pb)@W3 + b3) ----
    agg_f16_kernel<256, true, 0><<<aggGrid, 256, 0, stream>>>(
        Pb, 256, rp, colS, dinv, dinv, Ab, 256, nullptr, 0, N);
    mfma_gemm_kernel<256, 2, true, false, true><<<g1, 512, 0, stream>>>(
        Ab, 256, 256, nullptr, 0, 0, Wt3, b3, Pb, 256, alpha, 3,
        nullptr, Gb, 256, N, 256);

    // ---- L4 (SAGE 256->112), commuted: T = Gb@W4 (f16), U = Gb@R4+b4 ->
    //      d_out; then d_out += cinv * A * T ----
    mfma_gemm_kernel<256, 3, false, false, false><<<g1, 512, 0, stream>>>(
        Gb, 256, 256, nullptr, 0, 0, Wt4p, biasP, nullptr, 112, nullptr, 0,
        (float*)d_out, Ab, 128, N, 224);
    agg_f16_kernel<128, false, 1><<<aggGrid, 256, 0, stream>>>(
        Ab, 128, rp, colS, nullptr, cinv, nullptr, 0, (float*)d_out, 112, N);
}

// Round 7
// 675.363 us; speedup vs baseline: 1.1511x; 1.0040x over previous
//
#include <hip/hip_runtime.h>

// ---------------------------------------------------------------------------
// SAGE_Re GNN forward, R11.
// - agg: REVERT predication (R10 -3% regression) -> R9 unconditional UNR=4
//   gathers; keep OUT_MODE=1 RMW path for the commuted L4.
// - GEMM: THIRD LDS stage, prefetch distance 3, counted vmcnt ladder
//   (2L/L/0). Loads now get ~3 chunk-times (~900+ cyc) to cover HBM latency
//   -> B1 drain stall ~0. LDS 72KB (BN=256, 2 blk/CU) / 48KB (BN=128, 3).
// - L4 commuted via agg/GEMM commutation (R10, kept).
// - fp16 everywhere, swapped-operand C^T epilogue (R9, kept).
// - CSR: 3-phase multi-block scan (R5).
// ---------------------------------------------------------------------------

typedef _Float16 __attribute__((ext_vector_type(8))) f16x8;
typedef _Float16 __attribute__((ext_vector_type(2))) f16x2;
typedef __attribute__((ext_vector_type(4))) float f32x4;

__device__ __forceinline__ unsigned short f2h(float f) {
    union { _Float16 h; unsigned short u; } v; v.h = (_Float16)f; return v.u;
}
__device__ __forceinline__ float h2f(unsigned short u) {
    union { unsigned short u; _Float16 h; } v; v.u = u; return (float)v.h;
}

// ---------------- CSR build ----------------

__global__ __launch_bounds__(256) void zero_int_kernel(int* __restrict__ p, int n)
{
    int i = blockIdx.x * 256 + threadIdx.x;
    if (i < n) p[i] = 0;
}

__global__ __launch_bounds__(256) void count_deg_kernel(
    const int* __restrict__ row, int* __restrict__ deg, int E)
{
    int e = blockIdx.x * 256 + threadIdx.x;
    if (e < E) atomicAdd(&deg[row[e]], 1);
}

__global__ __launch_bounds__(1024) void scan_p1_kernel(
    const int* __restrict__ deg, int* __restrict__ rp,
    int* __restrict__ bsum, int n)
{
    __shared__ int wsum[16];
    int t = threadIdx.x, lane = t & 63, w = t >> 6;
    int base = blockIdx.x * 2048;
    int carry = 0;
    #pragma unroll
    for (int half = 0; half < 2; ++half) {
        int i = base + half * 1024 + t;
        int xv = (i < n) ? deg[i] : 0;
        int s = xv;
        #pragma unroll
        for (int off = 1; off < 64; off <<= 1) {
            int v = __shfl_up(s, off, 64);
            if (lane >= off) s += v;
        }
        if (lane == 63) wsum[w] = s;
        __syncthreads();
        if (w == 0 && lane < 16) {
            int ws = wsum[lane];
            #pragma unroll
            for (int off = 1; off < 16; off <<= 1) {
                int v = __shfl_up(ws, off, 64);
                if (lane >= off) ws += v;
            }
            wsum[lane] = ws;
        }
        __syncthreads();
        int wo = (w == 0) ? 0 : wsum[w - 1];
        if (i < n) rp[i + 1] = carry + wo + s;
        carry += wsum[15];
        if (half == 0) __syncthreads();
    }
    if (t == 0) bsum[blockIdx.x] = carry;
}

__global__ __launch_bounds__(64) void scan_p2_kernel(int* __restrict__ bsum, int B)
{
    int lane = threadIdx.x;
    int v = (lane < B) ? bsum[lane] : 0;
    int s = v;
    #pragma unroll
    for (int off = 1; off < 64; off <<= 1) {
        int u = __shfl_up(s, off, 64);
        if (lane >= off) s += u;
    }
    if (lane < B) bsum[lane] = s - v;
}

__global__ __launch_bounds__(1024) void scan_p3_kernel(
    const int* __restrict__ deg, int* __restrict__ rp,
    int* __restrict__ cursor, const int* __restrict__ bsum,
    float* __restrict__ dinv, float* __restrict__ cinv, int n)
{
    int boff = bsum[blockIdx.x];
    int base = blockIdx.x * 2048;
    #pragma unroll
    for (int half = 0; half < 2; ++half) {
        int i = base + half * 1024 + threadIdx.x;
        if (i < n) {
            int d = deg[i];
            int incl = rp[i + 1] + boff;
            rp[i + 1] = incl;
            cursor[i] = incl - d;
            float df = (float)d;
            dinv[i] = (d > 0) ? rsqrtf(df) : 0.0f;
            cinv[i] = 1.0f / fmaxf(df, 1.0f);
        }
    }
    if (blockIdx.x == 0 && threadIdx.x == 0) rp[0] = 0;
}

__global__ __launch_bounds__(256) void fill_csr_kernel(
    const int* __restrict__ row, const int* __restrict__ col,
    int* __restrict__ cursor, int* __restrict__ colS, int E)
{
    int e = blockIdx.x * 256 + threadIdx.x;
    if (e < E) {
        int p = atomicAdd(&cursor[row[e]], 1);
        colS[p] = col[e];
    }
}

// ---------------- prep ----------------

__global__ __launch_bounds__(256) void f32_to_f16_kernel(
    const float* __restrict__ src, unsigned short* __restrict__ dst, int n4)
{
    int i = blockIdx.x * 256 + threadIdx.x;
    if (i >= n4) return;
    float4 v = ((const float4*)src)[i];
    ushort4 o;
    o.x = f2h(v.x); o.y = f2h(v.y); o.z = f2h(v.z); o.w = f2h(v.w);
    ((ushort4*)dst)[i] = o;
}

__global__ __launch_bounds__(256) void prep_w_kernel(
    const float* __restrict__ S1, int K1,
    const float* __restrict__ S2, int K2,
    int Nout, int Npad, unsigned short* __restrict__ dst)
{
    int Ktot = K1 + K2;
    int idx = blockIdx.x * 256 + threadIdx.x;
    if (idx >= Npad * Ktot) return;
    int n = idx / Ktot, k = idx - n * Ktot;
    float v = 0.0f;
    if (n < Nout)
        v = (k < K1) ? S1[(size_t)k * Nout + n] : S2[(size_t)(k - K1) * Nout + n];
    dst[idx] = f2h(v);
}

// L4 weight prep: dst is 256 rows (n) x 256 cols (k):
//   n<112 -> W4[:,n] ; 112<=n<224 -> R4[:,n-112] ; else 0.
__global__ __launch_bounds__(256) void prep_w2_kernel(
    const float* __restrict__ W4, const float* __restrict__ R4,
    unsigned short* __restrict__ dst)
{
    int idx = blockIdx.x * 256 + threadIdx.x;   // 256*256 total
    int nrow = idx >> 8, k = idx & 255;
    float v = 0.0f;
    if (nrow < 112)      v = W4[(size_t)k * 112 + nrow];
    else if (nrow < 224) v = R4[(size_t)k * 112 + (nrow - 112)];
    dst[idx] = f2h(v);
}

__global__ __launch_bounds__(256) void prep_biasP_kernel(
    const float* __restrict__ b4, float* __restrict__ biasP)
{
    int i = threadIdx.x;   // 256
    biasP[i] = (i >= 112 && i < 224) ? b4[i - 112] : 0.0f;
}

// ---------------- aggregation: wave per node, packed-f16 accumulation ------
// OUT_MODE 0: out f16 (acc * nscale).   OUT_MODE 1: fout (f32, width 112)
//   += nscale * acc   (RMW of the GEMM-produced U term).

template <int C, bool HAS_ES, int OUT_MODE>
__global__ __launch_bounds__(256) void agg_f16_kernel(
    const unsigned short* __restrict__ h, int ldh,
    const int* __restrict__ rp, const int* __restrict__ cols,
    const float* __restrict__ escale, const float* __restrict__ nscale,
    unsigned short* __restrict__ out, int ldo,
    float* __restrict__ fout, int ldof, int n)
{
    constexpr int LPE = (C == 256) ? 32 : 16;  // lanes per edge
    constexpr int EPG = 64 / LPE;              // edges per group (2 or 4)
    constexpr int UNR = 4;                     // gathers in flight per lane
    int node = blockIdx.x * 4 + (threadIdx.x >> 6);
    if (node >= n) return;
    int lane = threadIdx.x & 63;
    int grp = lane / LPE, sub = lane % LPE;
    const unsigned short* hc = h + sub * 8;

    int s = rp[node], e = rp[node + 1];
    const _Float16 hz = (_Float16)0.0f;
    f16x2 zz = { hz, hz };
    f16x2 acc2[4];
    #pragma unroll
    for (int k = 0; k < 4; ++k) acc2[k] = zz;

    for (int i = s; i < e; i += UNR * EPG) {
        int cc[UNR]; f16x2 ssv[UNR]; uint4 uu[UNR];
        #pragma unroll
        for (int u = 0; u < UNR; ++u) {
            int ii = i + u * EPG + grp;
            bool valid = ii < e;
            int c = valid ? cols[ii] : 0;
            cc[u] = c;
            float sc = valid ? (HAS_ES ? escale[c] : 1.0f) : 0.0f;
            _Float16 sh = (_Float16)sc;
            f16x2 sv = { sh, sh };
            ssv[u] = sv;
        }
        #pragma unroll
        for (int u = 0; u < UNR; ++u)
            uu[u] = *(const uint4*)(hc + (size_t)cc[u] * ldh);
        #pragma unroll
        for (int u = 0; u < UNR; ++u) {
            union { uint4 q; f16x2 hh[4]; } cv; cv.q = uu[u];
            #pragma unroll
            for (int p = 0; p < 4; ++p)
                acc2[p] += cv.hh[p] * ssv[u];       // v_pk_fma_f16
        }
    }

    #pragma unroll
    for (int k = 0; k < 4; ++k) {
        union { f16x2 h2; float f; } a, b;
        a.h2 = acc2[k];
        if (EPG == 4) { b.f = __shfl_xor(a.f, 16, 64); a.h2 = a.h2 + b.h2; }
        b.f = __shfl_xor(a.f, 32, 64); a.h2 = a.h2 + b.h2;
        acc2[k] = a.h2;
    }

    if (OUT_MODE == 0) {
        if (grp == 0) {
            _Float16 nh = (_Float16)nscale[node];
            f16x2 nn = { nh, nh };
            union { uint4 q; f16x2 hh[4]; } o;
            #pragma unroll
            for (int p = 0; p < 4; ++p) o.hh[p] = acc2[p] * nn;
            *(uint4*)(out + (size_t)node * ldo + sub * 8) = o.q;
        }
    } else {
        // fout[node][sub*8 .. +7] += nscale * acc  (cols >= 112 skipped)
        if (grp == 0 && sub < 14) {
            float cs = nscale[node];
            float* U = fout + (size_t)node * ldof + sub * 8;
            float4 u0 = *(float4*)U;
            float4 u1 = *(float4*)(U + 4);
            u0.x += cs * (float)acc2[0][0];
            u0.y += cs * (float)acc2[0][1];
            u0.z += cs * (float)acc2[1][0];
            u0.w += cs * (float)acc2[1][1];
            u1.x += cs * (float)acc2[2][0];
            u1.y += cs * (float)acc2[2][1];
            u1.z += cs * (float)acc2[3][0];
            u1.w += cs * (float)acc2[3][1];
            *(float4*)U = u0;
            *(float4*)(U + 4) = u1;
        }
    }
}

// ---------------- fp16 MFMA GEMM, 128 x BN tile, 3-stage dist-3 pipeline ----
// MFMA operands SWAPPED: acc = mfma(B_frag, A_frag) computes the C^T
// fragment, so each lane holds 4 consecutive n at fixed m -> wide stores.
// EPI: 0 none, 1 relu, 2 residual (res + alpha*v), 3 dual-output L4
//   (n<112 -> f16 T at outb/ldo; n>=112 -> f32 U at outf/ldres).

__device__ __forceinline__ void g2l16(const unsigned short* g, unsigned short* l) {
    __builtin_amdgcn_global_load_lds(
        (const __attribute__((address_space(1))) unsigned int*)g,
        (__attribute__((address_space(3))) unsigned int*)l, 16, 0, 0);
}

template <int BN, int EPI, bool RES_F16, bool WF32, bool WB16>
__global__ __launch_bounds__(2 * BN) void mfma_gemm_kernel(
    const unsigned short* __restrict__ A1, int K1, int lda1,
    const unsigned short* __restrict__ A2, int K2, int lda2,
    const unsigned short* __restrict__ Bt,
    const float* __restrict__ bias,
    const void* __restrict__ res, int ldres,
    const float* __restrict__ alpha_ptr, int alpha_idx,
    float* __restrict__ outf, unsigned short* __restrict__ outb, int ldo,
    int M, int Nout)
{
    constexpr int WAVES = BN / 32;       // 4 (BN=128) or 8 (BN=256)
    constexpr int AI = 256 / BN;         // A-stage instrs per wave: 2 or 1
    constexpr int L  = AI + 2;           // loads per chunk per wave: 4 or 3
    __shared__ unsigned short As[3][128 * 32];
    __shared__ unsigned short Bs[3][BN * 32];
    int t = threadIdx.x;
    int m0 = blockIdx.x * 128, n0 = blockIdx.y * BN;
    int Ktot = K1 + K2;
    int w = t >> 6, lane = t & 63;
    int wm = w & 1, wn = w >> 1;         // wn in 0..WAVES/2-1
    int q = lane >> 4, l16 = lane & 15;

    // source-side swizzle: lane fetches 16B column-seg (lane&3)^((lane>>2)&3);
    // linear LDS then holds [row][seg ^ (row&3)] with no per-lane destination.
    int koff = (((lane & 3) ^ ((lane >> 2) & 3)) * 8);
    int rsub = lane >> 2;                // row within 16-row stripe: 0..15

    f32x4 acc[4][4];
    #pragma unroll
    for (int i = 0; i < 4; ++i)
        #pragma unroll
        for (int j = 0; j < 4; ++j)
            #pragma unroll
            for (int r = 0; r < 4; ++r) acc[i][j][r] = 0.0f;

    const int KC = Ktot >> 5;

    auto issue = [&](int kc, int p) {
        int k0 = kc * 32;
        const unsigned short* Ap; int lda, kk;
        if (k0 < K1) { Ap = A1; lda = lda1; kk = k0; }
        else         { Ap = A2; lda = lda2; kk = k0 - K1; }
        #pragma unroll
        for (int a = 0; a < AI; ++a) {
            int rb = a * 16 * WAVES + w * 16;         // LDS row base (uniform/wave)
            int gm = m0 + rb + rsub; if (gm >= M) gm = M - 1;
            g2l16(Ap + (size_t)gm * lda + kk + koff, &As[p][rb * 32]);
        }
        #pragma unroll
        for (int b = 0; b < 2; ++b) {
            int rb = b * 16 * WAVES + w * 16;
            int gn = n0 + rb + rsub;                   // < Npad by construction
            g2l16(Bt + (size_t)gn * Ktot + k0 + koff, &Bs[p][rb * 32]);
        }
    };

    // read-side swizzle: (row & 3) == (l16 & 3) for every fragment row
    const int cq = (q ^ (l16 & 3)) * 8;
    const int rbA = (wm * 64 + l16) * 32 + cq;
    const int rbB = (wn * 64 + l16) * 32 + cq;

    issue(0, 0);
    if (KC > 1) issue(1, 1);
    if (KC > 2) issue(2, 2);

    int p = 0;
    for (int kc = 0; kc < KC; ++kc) {
        int rem = KC - 1 - kc;   // chunks issued after kc (capped at 2)
        // steady state: chunks kc, kc+1, kc+2 outstanding -> drain kc only.
        if (rem >= 2) {
            if constexpr (L == 4) asm volatile("s_waitcnt vmcnt(8)" ::: "memory");
            else                  asm volatile("s_waitcnt vmcnt(6)" ::: "memory");
        } else if (rem == 1) {
            if constexpr (L == 4) asm volatile("s_waitcnt vmcnt(4)" ::: "memory");
            else                  asm volatile("s_waitcnt vmcnt(3)" ::: "memory");
        } else {
            asm volatile("s_waitcnt vmcnt(0)" ::: "memory");
        }
        __builtin_amdgcn_s_barrier();      // B1: chunk-kc data visible everywhere
        asm volatile("" ::: "memory");

        f16x8 af[4], bfr[4];
        #pragma unroll
        for (int i = 0; i < 4; ++i)
            af[i] = *(const f16x8*)&As[p][rbA + i * 16 * 32];
        #pragma unroll
        for (int j = 0; j < 4; ++j)
            bfr[j] = *(const f16x8*)&Bs[p][rbB + j * 16 * 32];

        asm volatile("s_waitcnt lgkmcnt(0)" ::: "memory");
        __builtin_amdgcn_s_barrier();      // B2: all waves done reading buf p
        asm volatile("" ::: "memory");
        if (kc + 3 < KC) issue(kc + 3, p); // distance-3 prefetch into freed buf

        __builtin_amdgcn_s_setprio(1);
        #pragma unroll
        for (int i = 0; i < 4; ++i)
            #pragma unroll
            for (int j = 0; j < 4; ++j)
                acc[i][j] = __builtin_amdgcn_mfma_f32_16x16x32_f16(
                    bfr[j], af[i], acc[i][j], 0, 0, 0);   // SWAPPED -> C^T frag
        __builtin_amdgcn_s_setprio(0);

        p = (p == 2) ? 0 : p + 1;
    }

    // Epilogue (swapped layout): lane (q,l16) holds, for tile (i,j),
    // m = m0 + wm*64 + i*16 + l16 (fixed), n = n0 + wn*64 + j*16 + q*4 + r.
    float alpha = 0.0f;
    if (EPI == 2) alpha = alpha_ptr[alpha_idx];
    #pragma unroll
    for (int i = 0; i < 4; ++i) {
        int m = m0 + wm * 64 + i * 16 + l16;
        if (m >= M) continue;
        #pragma unroll
        for (int j = 0; j < 4; ++j) {
            int nb = n0 + wn * 64 + j * 16 + q * 4;
            if (nb >= Nout) continue;      // Nout%16==0 or 224 -> uniform over q
            float4 bv = *(const float4*)&bias[nb];
            float v0 = acc[i][j][0] + bv.x;
            float v1 = acc[i][j][1] + bv.y;
            float v2 = acc[i][j][2] + bv.z;
            float v3 = acc[i][j][3] + bv.w;
            if (EPI == 3) {
                if (nb < 112) {
                    *(ushort4*)&outb[(size_t)m * ldo + nb] =
                        make_ushort4(f2h(v0), f2h(v1), f2h(v2), f2h(v3));
                } else {
                    *(float4*)&outf[(size_t)m * ldres + (nb - 112)] =
                        make_float4(v0, v1, v2, v3);
                }
                continue;
            }
            if (EPI == 1) {
                v0 = fmaxf(v0, 0.0f); v1 = fmaxf(v1, 0.0f);
                v2 = fmaxf(v2, 0.0f); v3 = fmaxf(v3, 0.0f);
            }
            if (EPI == 2) {
                if (RES_F16) {
                    ushort4 rr = *(const ushort4*)
                        ((const unsigned short*)res + (size_t)m * ldres + nb);
                    v0 = h2f(rr.x) + alpha * v0;
                    v1 = h2f(rr.y) + alpha * v1;
                    v2 = h2f(rr.z) + alpha * v2;
                    v3 = h2f(rr.w) + alpha * v3;
                } else {
                    float4 rr = *(const float4*)
                        ((const float*)res + (size_t)m * ldres + nb);
                    v0 = rr.x + alpha * v0;
                    v1 = rr.y + alpha * v1;
                    v2 = rr.z + alpha * v2;
                    v3 = rr.w + alpha * v3;
                }
            }
            if (WF32) {
                *(float4*)&outf[(size_t)m * ldo + nb] = make_float4(v0, v1, v2, v3);
            }
            if (WB16) {
                *(ushort4*)&outb[(size_t)m * ldo + nb] =
                    make_ushort4(f2h(v0), f2h(v1), f2h(v2), f2h(v3));
            }
        }
    }
}

// ---------------------------------------------------------------------------

extern "C" void kernel_launch(void* const* d_in, const int* in_sizes, int n_in,
                              void* d_out, int out_size, void* d_ws, size_t ws_size,
                              hipStream_t stream)
{
    const float* x      = (const float*)d_in[0];
    const int*   ei     = (const int*)d_in[1];
    const float* alpha  = (const float*)d_in[2];
    const float* W0     = (const float*)d_in[3];
    const float* b0     = (const float*)d_in[4];
    const float* W1     = (const float*)d_in[5];
    const float* R1     = (const float*)d_in[6];
    const float* b1     = (const float*)d_in[7];
    const float* W2     = (const float*)d_in[8];
    const float* R2     = (const float*)d_in[9];
    const float* b2     = (const float*)d_in[10];
    const float* W3     = (const float*)d_in[11];
    const float* b3     = (const float*)d_in[12];
    const float* W4     = (const float*)d_in[13];
    const float* R4     = (const float*)d_in[14];
    const float* b4     = (const float*)d_in[15];

    const int N = in_sizes[0] / 128;
    const int E = in_sizes[1] / 2;
    const int* row = ei;
    const int* col = ei + E;

    size_t off = 0;
    auto alloc = [&](size_t bytes) -> void* {
        void* p = (char*)d_ws + off;
        off += (bytes + 255) & ~(size_t)255;
        return p;
    };
    int*   deg    = (int*)alloc((size_t)N * 4);
    int*   rp     = (int*)alloc((size_t)(N + 1) * 4);
    int*   cursor = (int*)alloc((size_t)N * 4);
    int*   colS   = (int*)alloc((size_t)E * 4);
    int*   bsum   = (int*)alloc((size_t)64 * 4);
    float* dinv   = (float*)alloc((size_t)N * 4);
    float* cinv   = (float*)alloc((size_t)N * 4);
    unsigned short* Wt0 = (unsigned short*)alloc((size_t)128 * 128 * 2);
    unsigned short* Wt1 = (unsigned short*)alloc((size_t)256 * 256 * 2);
    unsigned short* Wt2 = (unsigned short*)alloc((size_t)256 * 512 * 2);
    unsigned short* Wt3 = (unsigned short*)alloc((size_t)256 * 256 * 2);
    unsigned short* Wt4p= (unsigned short*)alloc((size_t)256 * 256 * 2);
    float* biasP  = (float*)alloc((size_t)256 * 4);
    unsigned short* Xb  = (unsigned short*)alloc((size_t)N * 128 * 2);
    unsigned short* Gb  = (unsigned short*)alloc((size_t)N * 256 * 2);
    unsigned short* Pb  = (unsigned short*)alloc((size_t)N * 256 * 2);
    unsigned short* Ab  = (unsigned short*)alloc((size_t)N * 256 * 2);
    unsigned short* Hb  = Xb;  // alias: Xb only read by L0 agg before Hb written
    (void)ws_size;

    // ---- CSR build ----
    const int SB = (N + 2047) / 2048;
    zero_int_kernel<<<(N + 255) / 256, 256, 0, stream>>>(deg, N);
    count_deg_kernel<<<(E + 255) / 256, 256, 0, stream>>>(row, deg, E);
    scan_p1_kernel<<<SB, 1024, 0, stream>>>(deg, rp, bsum, N);
    scan_p2_kernel<<<1, 64, 0, stream>>>(bsum, SB);
    scan_p3_kernel<<<SB, 1024, 0, stream>>>(deg, rp, cursor, bsum, dinv, cinv, N);
    fill_csr_kernel<<<(E + 255) / 256, 256, 0, stream>>>(row, col, cursor, colS, E);

    // ---- prep ----
    f32_to_f16_kernel<<<(N * 32 + 255) / 256, 256, 0, stream>>>(x, Xb, N * 32);
    prep_w_kernel<<<(128 * 128 + 255) / 256, 256, 0, stream>>>(W0, 128, nullptr, 0, 128, 128, Wt0);
    prep_w_kernel<<<(256 * 256 + 255) / 256, 256, 0, stream>>>(W1, 128, R1, 128, 256, 256, Wt1);
    prep_w_kernel<<<(256 * 512 + 255) / 256, 256, 0, stream>>>(W2, 256, R2, 256, 256, 256, Wt2);
    prep_w_kernel<<<(256 * 256 + 255) / 256, 256, 0, stream>>>(W3, 256, nullptr, 0, 256, 256, Wt3);
    prep_w2_kernel<<<(256 * 256) / 256, 256, 0, stream>>>(W4, R4, Wt4p);
    prep_biasP_kernel<<<1, 256, 0, stream>>>(b4, biasP);

    dim3 aggGrid((N + 3) / 4);
    dim3 g1((N + 127) / 128, 1);

    // ---- L0 (GCN): Hb = f16( x + a0*(gcn_agg(x)@W0 + b0) ) ----
    agg_f16_kernel<128, true, 0><<<aggGrid, 256, 0, stream>>>(
        Xb, 128, rp, colS, dinv, dinv, Ab, 128, nullptr, 0, N);
    mfma_gemm_kernel<128, 2, false, false, true><<<g1, 256, 0, stream>>>(
        Ab, 128, 128, nullptr, 0, 0, Wt0, b0, x, 128, alpha, 0,
        nullptr, Hb, 128, N, 128);

    // ---- L1 (SAGE 128->256): Gb = relu([mean(Hb)|Hb]@[W1;R1]+b1) ----
    agg_f16_kernel<128, false, 0><<<aggGrid, 256, 0, stream>>>(
        Hb, 128, rp, colS, nullptr, cinv, Ab, 128, nullptr, 0, N);
    mfma_gemm_kernel<256, 1, false, false, true><<<g1, 512, 0, stream>>>(
        Ab, 128, 128, Hb, 128, 128, Wt1, b1, nullptr, 0, nullptr, 0,
        nullptr, Gb, 256, N, 256);

    // ---- L2 (SAGE 256->256): Pb = relu([mean(Gb)|Gb]@[W2;R2]+b2) ----
    agg_f16_kernel<256, false, 0><<<aggGrid, 256, 0, stream>>>(
        Gb, 256, rp, colS, nullptr, cinv, Ab, 256, nullptr, 0, N);
    mfma_gemm_kernel<256, 1, false, false, true><<<g1, 512, 0, stream>>>(
        Ab, 256, 256, Gb, 256, 256, Wt2, b2, nullptr, 0, nullptr, 0,
        nullptr, Pb, 256, N, 256);

    // ---- L3 (GCN): Gb = Pb + a3*(gcn_agg(Pb)@W3 + b3) ----
    agg_f16_kernel<256, true, 0><<<aggGrid, 256, 0, stream>>>(
        Pb, 256, rp, colS, dinv, dinv, Ab, 256, nullptr, 0, N);
    mfma_gemm_kernel<256, 2, true, false, true><<<g1, 512, 0, stream>>>(
        Ab, 256, 256, nullptr, 0, 0, Wt3, b3, Pb, 256, alpha, 3,
        nullptr, Gb, 256, N, 256);

    // ---- L4 (SAGE 256->112), commuted: T = Gb@W4 (f16), U = Gb@R4+b4 ->
    //      d_out; then d_out += cinv * A * T ----
    mfma_gemm_kernel<256, 3, false, false, false><<<g1, 512, 0, stream>>>(
        Gb, 256, 256, nullptr, 0, 0, Wt4p, biasP, nullptr, 112, nullptr, 0,
        (float*)d_out, Ab, 128, N, 224);
    agg_f16_kernel<128, false, 1><<<aggGrid, 256, 0, stream>>>(
        Ab, 128, rp, colS, nullptr, cinv, nullptr, 0, (float*)d_out, 112, N);
}